// Round 9
// baseline (1129.048 us; speedup 1.0000x reference)
//
#include <hip/hip_runtime.h>
#include <math.h>

#define Bdim 4
#define Sdim 2048
#define Ddim 1024
#define Hdim 16
#define HDdim 64

typedef unsigned long long u64;
typedef unsigned short ushort_t;
typedef int int4v __attribute__((ext_vector_type(4)));
typedef short short8v __attribute__((ext_vector_type(8)));
typedef float float4v __attribute__((ext_vector_type(4)));
typedef unsigned short us4v __attribute__((ext_vector_type(4)));

// ---------------------------------------------------------------------------
// helpers
// ---------------------------------------------------------------------------
__device__ __forceinline__ float qdq_f(float x, float amax) {
  float s = fmaxf(amax / 127.0f, 1e-8f);
  float r = rintf(x / s);                 // exact-division path (residual-visible)
  r = fminf(fmaxf(r, -128.0f), 127.0f);
  return r * s;
}

__device__ __forceinline__ void atomicMaxF(float* a, float v) {
  atomicMax((int*)a, __float_as_int(v));   // valid: non-negative floats
}

__device__ __forceinline__ float blockMax256(float v) {
  __shared__ float sred[4];
  #pragma unroll
  for (int o = 32; o > 0; o >>= 1) v = fmaxf(v, __shfl_xor(v, o));
  if ((threadIdx.x & 63) == 0) sred[threadIdx.x >> 6] = v;
  __syncthreads();
  return fmaxf(fmaxf(sred[0], sred[1]), fmaxf(sred[2], sred[3]));
}

__device__ __forceinline__ ushort_t f2bf(float f) {  // RNE fp32->bf16
  unsigned u = __float_as_uint(f);
  return (ushort_t)((u + 0x7FFFu + ((u >> 16) & 1u)) >> 16);
}
__device__ __forceinline__ float bf2f(ushort_t h) {
  return __uint_as_float(((unsigned)h) << 16);
}

// blk 0: zero scalars; blk 1..12: concat [bq;bk;bv] -> BQKV
__global__ void init_kernel(float* __restrict__ s,
                            const float* __restrict__ bq, const float* __restrict__ bk,
                            const float* __restrict__ bv, float* __restrict__ o) {
  if (blockIdx.x == 0) { s[threadIdx.x] = 0.0f; return; }
  int t = (blockIdx.x - 1) * 256 + threadIdx.x;   // 0..3071
  o[t] = (t < 1024) ? bq[t] : (t < 2048) ? bk[t - 1024] : bv[t - 2048];
}

// ---------------------------------------------------------------------------
// merged absmax of 6 weights (segmented grid-stride)
// ---------------------------------------------------------------------------
__global__ __launch_bounds__(256) void absmax6_kernel(
    const float* __restrict__ Wq, const float* __restrict__ Wk,
    const float* __restrict__ Wv, const float* __restrict__ Wo,
    const float* __restrict__ W1, const float* __restrict__ W2,
    float* __restrict__ Sc)
{
  const u64 DD = (u64)Ddim * Ddim;
  int blk = blockIdx.x;
  const float* src; float* dst; u64 lb, nb, n;
  if (blk < 256)       { src = Wq; dst = Sc + 1; lb = blk;        nb = 256;  n = DD; }
  else if (blk < 512)  { src = Wk; dst = Sc + 2; lb = blk - 256;  nb = 256;  n = DD; }
  else if (blk < 768)  { src = Wv; dst = Sc + 3; lb = blk - 512;  nb = 256;  n = DD; }
  else if (blk < 1024) { src = Wo; dst = Sc + 4; lb = blk - 768;  nb = 256;  n = DD; }
  else if (blk < 2048) { src = W1; dst = Sc + 5; lb = blk - 1024; nb = 1024; n = 4 * DD; }
  else                 { src = W2; dst = Sc + 6; lb = blk - 2048; nb = 1024; n = 4 * DD; }
  u64 i = lb * 256 + threadIdx.x;
  u64 stride = nb * 256;
  float m = 0.0f;
  for (; i < n; i += stride) m = fmaxf(m, fabsf(src[i]));
  m = blockMax256(m);
  if (threadIdx.x == 0) atomicMaxF(dst, m);
}

// ---------------------------------------------------------------------------
// merged weight quantization: Wq/Wk/Wv/W1/W2 -> int8, Wo -> int-in-bf16
// ---------------------------------------------------------------------------
__global__ __launch_bounds__(256) void quantw_kernel(
    const float* __restrict__ Wq, const float* __restrict__ Wk,
    const float* __restrict__ Wv, const float* __restrict__ Wo,
    const float* __restrict__ W1, const float* __restrict__ W2,
    signed char* __restrict__ Wq8, signed char* __restrict__ Wk8,
    signed char* __restrict__ Wv8, ushort_t* __restrict__ WoBF,
    signed char* __restrict__ W18, signed char* __restrict__ W28,
    const float* __restrict__ Sc)
{
  const u64 DD = (u64)Ddim * Ddim;
  int blk = blockIdx.x;
  if (blk < 2816) {   // int8 path (float4 units)
    const float* src; signed char* dst; float sa; u64 lb, nb, n4;
    if (blk < 256)       { src = Wq; dst = Wq8; sa = Sc[1]; lb = blk;        nb = 256;  n4 = DD / 4; }
    else if (blk < 512)  { src = Wk; dst = Wk8; sa = Sc[2]; lb = blk - 256;  nb = 256;  n4 = DD / 4; }
    else if (blk < 768)  { src = Wv; dst = Wv8; sa = Sc[3]; lb = blk - 512;  nb = 256;  n4 = DD / 4; }
    else if (blk < 1792) { src = W1; dst = W18; sa = Sc[5]; lb = blk - 768;  nb = 1024; n4 = DD; }
    else                 { src = W2; dst = W28; sa = Sc[6]; lb = blk - 1792; nb = 1024; n4 = DD; }
    const float is = 1.0f / fmaxf(sa / 127.0f, 1e-8f);
    u64 i = lb * 256 + threadIdx.x;
    u64 stride = nb * 256;
    for (; i < n4; i += stride) {
      float4 v = ((const float4*)src)[i];
      int b0 = (int)fminf(fmaxf(rintf(v.x * is), -128.0f), 127.0f) & 255;
      int b1 = (int)fminf(fmaxf(rintf(v.y * is), -128.0f), 127.0f) & 255;
      int b2 = (int)fminf(fmaxf(rintf(v.z * is), -128.0f), 127.0f) & 255;
      int b3 = (int)fminf(fmaxf(rintf(v.w * is), -128.0f), 127.0f) & 255;
      ((unsigned*)dst)[i] = (unsigned)(b0 | (b1 << 8) | (b2 << 16) | (b3 << 24));
    }
  } else {            // Wo -> exact int in bf16
    const float is = 1.0f / fmaxf(Sc[4] / 127.0f, 1e-8f);
    u64 i = (u64)(blk - 2816) * 256 + threadIdx.x;
    u64 stride = 1024ull * 256;
    for (; i < DD; i += stride) {
      float r = fminf(fmaxf(rintf(Wo[i] * is), -128.0f), 127.0f);
      WoBF[i] = f2bf(r);
    }
  }
}

// ---------------------------------------------------------------------------
// quantize fp32 -> int8 (packed 4/thread) — activations feeding GEMMs
// ---------------------------------------------------------------------------
__global__ __launch_bounds__(256) void quant8_kernel(
    const float* __restrict__ x, const float* __restrict__ amaxp,
    signed char* __restrict__ q, u64 n4)
{
  const float is = 1.0f / fmaxf(*amaxp / 127.0f, 1e-8f);
  u64 i = (u64)blockIdx.x * 256 + threadIdx.x;
  u64 stride = (u64)gridDim.x * 256;
  for (; i < n4; i += stride) {
    float4 v = ((const float4*)x)[i];
    int b0 = (int)fminf(fmaxf(rintf(v.x * is), -128.0f), 127.0f) & 255;
    int b1 = (int)fminf(fmaxf(rintf(v.y * is), -128.0f), 127.0f) & 255;
    int b2 = (int)fminf(fmaxf(rintf(v.z * is), -128.0f), 127.0f) & 255;
    int b3 = (int)fminf(fmaxf(rintf(v.w * is), -128.0f), 127.0f) & 255;
    ((unsigned*)q)[i] = (unsigned)(b0 | (b1 << 8) | (b2 << 16) | (b3 << 24));
  }
}

// ---------------------------------------------------------------------------
// LayerNorm (one block per row of 1024), optional input qdq, output absmax
// ---------------------------------------------------------------------------
__global__ __launch_bounds__(256) void ln_kernel(
    const float* __restrict__ x, const float* __restrict__ g,
    const float* __restrict__ beta, const float* __restrict__ inAmax,
    float* __restrict__ y, float* __restrict__ amaxOut)
{
  __shared__ float sred[4];
  __shared__ float smv[2];
  const int tid = threadIdx.x;
  const u64 row = blockIdx.x;
  const float* xr = x + row * Ddim;
  float* yr = y + row * Ddim;
  float aIn = inAmax ? *inAmax : 0.0f;

  float vals[4];
  float sum = 0.0f;
  #pragma unroll
  for (int i = 0; i < 4; i++) {
    float v = xr[tid + (i << 8)];
    if (inAmax) v = qdq_f(v, aIn);
    vals[i] = v;
    sum += v;
  }
  #pragma unroll
  for (int o = 32; o > 0; o >>= 1) sum += __shfl_xor(sum, o);
  if ((tid & 63) == 0) sred[tid >> 6] = sum;
  __syncthreads();
  if (tid == 0) smv[0] = (sred[0] + sred[1] + sred[2] + sred[3]) * (1.0f / 1024.0f);
  __syncthreads();
  const float mean = smv[0];

  float dev = 0.0f;
  #pragma unroll
  for (int i = 0; i < 4; i++) { float d = vals[i] - mean; dev += d * d; }
  #pragma unroll
  for (int o = 32; o > 0; o >>= 1) dev += __shfl_xor(dev, o);
  if ((tid & 63) == 0) sred[tid >> 6] = dev;
  __syncthreads();
  if (tid == 0) {
    float var = (sred[0] + sred[1] + sred[2] + sred[3]) * (1.0f / 1024.0f);
    smv[1] = 1.0f / sqrtf(var + 1e-5f);
  }
  __syncthreads();
  const float inv = smv[1];

  float lmax = 0.0f;
  #pragma unroll
  for (int i = 0; i < 4; i++) {
    int c = tid + (i << 8);
    float ov = (vals[i] - mean) * inv * g[c] + beta[c];
    yr[c] = ov;
    lmax = fmaxf(lmax, fabsf(ov));
  }
  #pragma unroll
  for (int o = 32; o > 0; o >>= 1) lmax = fmaxf(lmax, __shfl_xor(lmax, o));
  __syncthreads();
  if ((tid & 63) == 0) sred[tid >> 6] = lmax;
  __syncthreads();
  if (tid == 0)
    atomicMaxF(amaxOut, fmaxf(fmaxf(sred[0], sred[1]), fmaxf(sred[2], sred[3])));
}

// ---------------------------------------------------------------------------
// i8 MFMA GEMM: C[M,N] = (A8[M,K] @ B8[N,K]^T)*sA*sB + bias[N]
// 128x128 tile, BK=64, 2x2 waves x 4x4 mfma_i32_16x16x64_i8 tiles.
// EPI: 0 none; 1 gelu+amax; 2 +qdq(T)+amax (fused residual add)
// ---------------------------------------------------------------------------
template <int EPI>
__global__ __launch_bounds__(256) void gemm_i8(
    const signed char* __restrict__ A8, const signed char* __restrict__ B8,
    const float* __restrict__ bias, float* __restrict__ C,
    int M, int N, int K,
    const float* __restrict__ sAp, const float* __restrict__ sBp,
    float* __restrict__ amaxOut,
    const float* __restrict__ Tm = nullptr,
    const float* __restrict__ amaxT = nullptr)
{
  __shared__ __align__(16) signed char As[128][80];
  __shared__ __align__(16) signed char Bs[128][80];
  const int tid = threadIdx.x;
  const int wave = tid >> 6, lane = tid & 63;
  const int quad = lane >> 4, l16 = lane & 15;
  const int wy = wave >> 1, wx = wave & 1;
  const int m0 = blockIdx.y << 7, n0 = blockIdx.x << 7;
  const float sA = fmaxf(*sAp / 127.0f, 1e-8f);
  const float sB = fmaxf(*sBp / 127.0f, 1e-8f);
  const float sAB = sA * sB;
  const float aT = (EPI == 2) ? *amaxT : 0.0f;

  const int sr = tid >> 2;            // staging row 0..63
  const int sc = (tid & 3) << 4;      // staging byte col 0/16/32/48

  int4v acc[4][4] = {};
  for (int k0 = 0; k0 < K; k0 += 64) {
    #pragma unroll
    for (int p = 0; p < 2; p++) {
      int r = sr + (p << 6);
      uint4 av = *(const uint4*)&A8[(u64)(m0 + r) * K + k0 + sc];
      uint4 bv = *(const uint4*)&B8[(u64)(n0 + r) * K + k0 + sc];
      *(uint4*)&As[r][sc] = av;
      *(uint4*)&Bs[r][sc] = bv;
    }
    __syncthreads();
    int4v af[4], bf[4];
    #pragma unroll
    for (int mt = 0; mt < 4; mt++)
      af[mt] = *(const int4v*)&As[(wy << 6) + (mt << 4) + l16][quad << 4];
    #pragma unroll
    for (int nt = 0; nt < 4; nt++)
      bf[nt] = *(const int4v*)&Bs[(wx << 6) + (nt << 4) + l16][quad << 4];
    #pragma unroll
    for (int mt = 0; mt < 4; mt++)
      #pragma unroll
      for (int nt = 0; nt < 4; nt++)
        acc[mt][nt] = __builtin_amdgcn_mfma_i32_16x16x64_i8(af[mt], bf[nt], acc[mt][nt], 0, 0, 0);
    __syncthreads();
  }

  float lmax = 0.0f;
  #pragma unroll
  for (int mt = 0; mt < 4; mt++) {
    #pragma unroll
    for (int reg = 0; reg < 4; reg++) {
      int row = m0 + (wy << 6) + (mt << 4) + (quad << 2) + reg;
      #pragma unroll
      for (int nt = 0; nt < 4; nt++) {
        int col = n0 + (wx << 6) + (nt << 4) + l16;
        float v = (float)acc[mt][nt][reg] * sAB + bias[col];
        if (EPI == 1) {
          v = 0.5f * v * (1.0f + erff(v * 0.70710678118654752440f));
          lmax = fmaxf(lmax, fabsf(v));
        }
        if (EPI == 2) {
          v += qdq_f(Tm[(u64)row * N + col], aT);
          lmax = fmaxf(lmax, fabsf(v));
        }
        C[(u64)row * N + col] = v;
      }
    }
  }
  if (EPI >= 1) {
    lmax = blockMax256(lmax);
    if (tid == 0) atomicMaxF(amaxOut, lmax);
  }
}

// ---------------------------------------------------------------------------
// plain mega-QKV i8 GEMM: C[M,3072] = A8 @ [Wq8;Wk8;Wv8]^T + BQKV
// per-segment weight scale (seg = n0>>10). Epilogue = store only (no
// transcendentals -> no libcall spills; see R7 post-mortem).
// ---------------------------------------------------------------------------
__global__ __launch_bounds__(256) void gemm_qkv3(
    const signed char* __restrict__ A8, const signed char* __restrict__ B8,
    const float* __restrict__ bias, float* __restrict__ C,
    const float* __restrict__ Sc)
{
  __shared__ __align__(16) signed char As[128][80];
  __shared__ __align__(16) signed char Bs[128][80];
  const int tid = threadIdx.x;
  const int wave = tid >> 6, lane = tid & 63;
  const int quad = lane >> 4, l16 = lane & 15;
  const int wy = wave >> 1, wx = wave & 1;
  const int m0 = blockIdx.y << 7, n0 = blockIdx.x << 7;
  const int K = Ddim, N = 3 * Ddim;
  const int seg = n0 >> 10;
  const float sA = fmaxf(Sc[0] / 127.0f, 1e-8f);
  const float sB = fmaxf(Sc[1 + seg] / 127.0f, 1e-8f);
  const float sAB = sA * sB;

  const int sr = tid >> 2;
  const int sc_ = (tid & 3) << 4;

  int4v acc[4][4] = {};
  for (int k0 = 0; k0 < K; k0 += 64) {
    #pragma unroll
    for (int p = 0; p < 2; p++) {
      int r = sr + (p << 6);
      uint4 av = *(const uint4*)&A8[(u64)(m0 + r) * K + k0 + sc_];
      uint4 bv = *(const uint4*)&B8[(u64)(n0 + r) * K + k0 + sc_];
      *(uint4*)&As[r][sc_] = av;
      *(uint4*)&Bs[r][sc_] = bv;
    }
    __syncthreads();
    int4v af[4], bf[4];
    #pragma unroll
    for (int mt = 0; mt < 4; mt++)
      af[mt] = *(const int4v*)&As[(wy << 6) + (mt << 4) + l16][quad << 4];
    #pragma unroll
    for (int nt = 0; nt < 4; nt++)
      bf[nt] = *(const int4v*)&Bs[(wx << 6) + (nt << 4) + l16][quad << 4];
    #pragma unroll
    for (int mt = 0; mt < 4; mt++)
      #pragma unroll
      for (int nt = 0; nt < 4; nt++)
        acc[mt][nt] = __builtin_amdgcn_mfma_i32_16x16x64_i8(af[mt], bf[nt], acc[mt][nt], 0, 0, 0);
    __syncthreads();
  }

  #pragma unroll
  for (int mt = 0; mt < 4; mt++) {
    #pragma unroll
    for (int reg = 0; reg < 4; reg++) {
      int row = m0 + (wy << 6) + (mt << 4) + (quad << 2) + reg;
      #pragma unroll
      for (int nt = 0; nt < 4; nt++) {
        int col = n0 + (wx << 6) + (nt << 4) + l16;
        C[(u64)row * N + col] = (float)acc[mt][nt][reg] * sAB + bias[col];
      }
    }
  }
}

// ---------------------------------------------------------------------------
// bf16-split MFMA GEMM for Wo: C = ((Ahi+Alo)[M,K] @ Wq[N,K]^T)*sW + bias
// ---------------------------------------------------------------------------
__global__ __launch_bounds__(256) void gemm_bf16_wo(
    const ushort_t* __restrict__ Ahi, const ushort_t* __restrict__ Alo,
    const ushort_t* __restrict__ Bw, const float* __restrict__ bias,
    float* __restrict__ C, int M, int N, int K,
    const float* __restrict__ sWp, float* __restrict__ amaxOut)
{
  __shared__ __align__(16) ushort_t Hs[128][40];
  __shared__ __align__(16) ushort_t Ls[128][40];
  __shared__ __align__(16) ushort_t Ws[128][40];
  const int tid = threadIdx.x;
  const int wave = tid >> 6, lane = tid & 63;
  const int quad = lane >> 4, l16 = lane & 15;
  const int wy = wave >> 1, wx = wave & 1;
  const int m0 = blockIdx.y << 7, n0 = blockIdx.x << 7;
  const float sW = fmaxf(*sWp / 127.0f, 1e-8f);

  const int sr = tid >> 2;
  const int sce = (tid & 3) << 3;

  float4v acc[4][4] = {};
  for (int k0 = 0; k0 < K; k0 += 32) {
    #pragma unroll
    for (int p = 0; p < 2; p++) {
      int r = sr + (p << 6);
      uint4 hv = *(const uint4*)&Ahi[(u64)(m0 + r) * K + k0 + sce];
      uint4 lv = *(const uint4*)&Alo[(u64)(m0 + r) * K + k0 + sce];
      uint4 wv = *(const uint4*)&Bw[(u64)(n0 + r) * K + k0 + sce];
      *(uint4*)&Hs[r][sce] = hv;
      *(uint4*)&Ls[r][sce] = lv;
      *(uint4*)&Ws[r][sce] = wv;
    }
    __syncthreads();
    short8v ah[4], al[4], bw[4];
    #pragma unroll
    for (int mt = 0; mt < 4; mt++) {
      ah[mt] = *(const short8v*)&Hs[(wy << 6) + (mt << 4) + l16][quad << 3];
      al[mt] = *(const short8v*)&Ls[(wy << 6) + (mt << 4) + l16][quad << 3];
    }
    #pragma unroll
    for (int nt = 0; nt < 4; nt++)
      bw[nt] = *(const short8v*)&Ws[(wx << 6) + (nt << 4) + l16][quad << 3];
    #pragma unroll
    for (int mt = 0; mt < 4; mt++)
      #pragma unroll
      for (int nt = 0; nt < 4; nt++) {
        acc[mt][nt] = __builtin_amdgcn_mfma_f32_16x16x32_bf16(ah[mt], bw[nt], acc[mt][nt], 0, 0, 0);
        acc[mt][nt] = __builtin_amdgcn_mfma_f32_16x16x32_bf16(al[mt], bw[nt], acc[mt][nt], 0, 0, 0);
      }
    __syncthreads();
  }

  float lmax = 0.0f;
  #pragma unroll
  for (int mt = 0; mt < 4; mt++) {
    #pragma unroll
    for (int reg = 0; reg < 4; reg++) {
      int row = m0 + (wy << 6) + (mt << 4) + (quad << 2) + reg;
      #pragma unroll
      for (int nt = 0; nt < 4; nt++) {
        int col = n0 + (wx << 6) + (nt << 4) + l16;
        float v = acc[mt][nt][reg] * sW + bias[col];
        lmax = fmaxf(lmax, fabsf(v));
        C[(u64)row * N + col] = v;
      }
    }
  }
  lmax = blockMax256(lmax);
  if (tid == 0) atomicMaxF(amaxOut, lmax);
}

// ---------------------------------------------------------------------------
// prep_attn: rope(q)*0.125, rope(k), hi/lo bf16 split, V transpose, norms.
// In:  QKV fp32 [row][3072] (cols 0..1023 q, 1024..2047 k, 2048..3071 v)
// Out: QH/QL/KH/KL ushort [bh][s][hd];  VTH/VTL ushort [bh][hd][s]
// grid (S/64, B*H), block 256. (memory-bound; libcalls harmless here — R7)
// ---------------------------------------------------------------------------
__global__ __launch_bounds__(256) void prep_attn(
    const float* __restrict__ QKV,
    ushort_t* __restrict__ QH, ushort_t* __restrict__ QL,
    ushort_t* __restrict__ KH, ushort_t* __restrict__ KL,
    ushort_t* __restrict__ VTH, ushort_t* __restrict__ VTL,
    float* __restrict__ NQ, float* __restrict__ KMX)
{
  const int bh = blockIdx.y;
  const int b = bh >> 4, h = bh & 15;
  const int s0 = blockIdx.x << 6;
  const int tid = threadIdx.x;
  float kml = 0.0f;

  // --- q/k rope + scale + split + norms (2048 pairs) ---
  #pragma unroll
  for (int i = 0; i < 8; i++) {
    int idx = tid + (i << 8);          // 0..2047
    int s = idx >> 5, hp = idx & 31;
    int sa = s0 + s;
    u64 gin = (u64)(b * Sdim + sa) * 3072 + (h << 6) + hp;
    float inv = powf(10000.0f, -(float)hp * (1.0f / 32.0f));
    float ang = (float)sa * inv;
    float cs = cosf(ang), sn = sinf(ang);
    float q1 = QKV[gin],        q2 = QKV[gin + 32];
    float k1 = QKV[gin + 1024], k2 = QKV[gin + 1056];
    float qo1 = (q1 * cs - q2 * sn) * 0.125f;
    float qo2 = (q1 * sn + q2 * cs) * 0.125f;
    float ko1 = k1 * cs - k2 * sn;
    float ko2 = k1 * sn + k2 * cs;
    u64 go = ((u64)bh * Sdim + sa) * HDdim + hp;
    ushort_t t;
    t = f2bf(qo1); QH[go]      = t; QL[go]      = f2bf(qo1 - bf2f(t));
    t = f2bf(qo2); QH[go + 32] = t; QL[go + 32] = f2bf(qo2 - bf2f(t));
    t = f2bf(ko1); KH[go]      = t; KL[go]      = f2bf(ko1 - bf2f(t));
    t = f2bf(ko2); KH[go + 32] = t; KL[go + 32] = f2bf(ko2 - bf2f(t));
    float nq2 = qo1 * qo1 + qo2 * qo2;
    float nk2 = ko1 * ko1 + ko2 * ko2;
    #pragma unroll
    for (int o = 16; o >= 1; o >>= 1) {
      nq2 += __shfl_xor(nq2, o);
      nk2 += __shfl_xor(nk2, o);
    }
    if (hp == 0) {
      NQ[(u64)bh * Sdim + sa] = sqrtf(nq2);
      kml = fmaxf(kml, sqrtf(nk2));
    }
  }
  kml = blockMax256(kml);
  if (tid == 0) atomicMaxF(&KMX[bh], kml);

  // --- v: split + transpose via LDS ---
  __shared__ ushort_t VHs[64][66], VLs[64][66];
  #pragma unroll
  for (int i = 0; i < 4; i++) {
    int idx4 = tid + (i << 8);         // 0..1023
    int s = idx4 >> 4, c4 = (idx4 & 15) << 2;
    u64 gin = (u64)(b * Sdim + s0 + s) * 3072 + 2048 + (h << 6) + c4;
    float4 vv = *(const float4*)&QKV[gin];
    float va[4] = {vv.x, vv.y, vv.z, vv.w};
    #pragma unroll
    for (int j = 0; j < 4; j++) {
      ushort_t vh = f2bf(va[j]);
      VHs[s][c4 + j] = vh;
      VLs[s][c4 + j] = f2bf(va[j] - bf2f(vh));
    }
  }
  __syncthreads();
  #pragma unroll
  for (int i = 0; i < 4; i++) {
    int idx4 = tid + (i << 8);
    int hd = idx4 >> 4, s4 = (idx4 & 15) << 2;
    us4v oh, ol;
    #pragma unroll
    for (int j = 0; j < 4; j++) { oh[j] = VHs[s4 + j][hd]; ol[j] = VLs[s4 + j][hd]; }
    u64 go = ((u64)bh * HDdim + hd) * Sdim + s0 + s4;
    *(us4v*)&VTH[go] = oh;
    *(us4v*)&VTL[go] = ol;
  }
}

// ---------------------------------------------------------------------------
// MFMA flash attention v4: 256 q-rows/block (4 waves x 64 rows, mt=4),
// KV tile = 32. Q frags in registers; static-max softmax; P fp32 in LDS
// (per-wave rows, no barrier). LDS = 9216(K) + 10240(V^T) + 36864(P)
// = 56320 -> 2 blocks/CU. B-frag LDS traffic per q-row halved vs v3.
// No transcendental libcalls (R7 lesson).
// ---------------------------------------------------------------------------
__global__ __launch_bounds__(256) void attn_kernel(
    const ushort_t* __restrict__ QH, const ushort_t* __restrict__ QL,
    const ushort_t* __restrict__ KH, const ushort_t* __restrict__ KL,
    const ushort_t* __restrict__ VTH, const ushort_t* __restrict__ VTL,
    const float* __restrict__ NQ, const float* __restrict__ KMX,
    ushort_t* __restrict__ OHI, ushort_t* __restrict__ OLO)
{
  __shared__ __align__(16) ushort_t KHs[32][72], KLs[32][72];
  __shared__ __align__(16) ushort_t VHs[64][40], VLs[64][40];   // V^T [hd][kv]
  __shared__ __align__(16) float PF[256][36];
  const int tid = threadIdx.x;
  const int wave = tid >> 6, lane = tid & 63;
  const int quad = lane >> 4, l16 = lane & 15;
  const int w64 = wave << 6;                 // wave's 64 q-rows
  const int bh = blockIdx.y;
  const int b = bh >> 4, h = bh & 15;
  const int q0 = blockIdx.x << 8;            // 256 q-rows per block
  const u64 bhS = (u64)bh * Sdim;

  // ---- Q fragments -> registers (A-layout: m=l16, k=quad*8+j) ----
  short8v qh[4][2], ql[4][2];
  #pragma unroll
  for (int mt = 0; mt < 4; mt++)
    #pragma unroll
    for (int kk = 0; kk < 2; kk++) {
      u64 g = (bhS + q0 + w64 + (mt << 4) + l16) * HDdim + (kk << 5) + (quad << 3);
      qh[mt][kk] = *(const short8v*)&QH[g];
      ql[mt][kk] = *(const short8v*)&QL[g];
    }

  const float kmax = KMX[bh] * 1.0009765625f;
  float Mb[4][4], lsum[4][4];
  #pragma unroll
  for (int mt = 0; mt < 4; mt++)
    #pragma unroll
    for (int r = 0; r < 4; r++) {
      Mb[mt][r] = NQ[bhS + q0 + w64 + (mt << 4) + (quad << 2) + r] * kmax;
      lsum[mt][r] = 0.0f;
    }

  float4v oacc[4][4] = {};

  for (int j0 = 0; j0 < Sdim; j0 += 32) {
    __syncthreads();
    {
      int r = tid >> 3, c8 = (tid & 7) << 3;       // K tile: 32 rows x 64 hd
      u64 gk = (bhS + j0 + r) * HDdim + c8;
      *(uint4*)&KHs[r][c8] = *(const uint4*)&KH[gk];
      *(uint4*)&KLs[r][c8] = *(const uint4*)&KL[gk];
      int r2 = tid >> 2, c82 = (tid & 3) << 3;     // V^T tile: 64 hd x 32 kv
      u64 gv = ((u64)bh * HDdim + r2) * Sdim + j0 + c82;
      *(uint4*)&VHs[r2][c82] = *(const uint4*)&VTH[gv];
      *(uint4*)&VLs[r2][c82] = *(const uint4*)&VTL[gv];
    }
    __syncthreads();

    // ---- scores = Q K^T (3-term hi/lo); nt spans 2 kv 16-tiles ----
    float4v sc[4][2] = {};
    #pragma unroll
    for (int kk = 0; kk < 2; kk++) {
      short8v kf_h[2], kf_l[2];
      #pragma unroll
      for (int nt = 0; nt < 2; nt++) {
        kf_h[nt] = *(const short8v*)&KHs[(nt << 4) + l16][(kk << 5) + (quad << 3)];
        kf_l[nt] = *(const short8v*)&KLs[(nt << 4) + l16][(kk << 5) + (quad << 3)];
      }
      #pragma unroll
      for (int mt = 0; mt < 4; mt++)
        #pragma unroll
        for (int nt = 0; nt < 2; nt++) {
          sc[mt][nt] = __builtin_amdgcn_mfma_f32_16x16x32_bf16(qh[mt][kk], kf_h[nt], sc[mt][nt], 0, 0, 0);
          sc[mt][nt] = __builtin_amdgcn_mfma_f32_16x16x32_bf16(qh[mt][kk], kf_l[nt], sc[mt][nt], 0, 0, 0);
          sc[mt][nt] = __builtin_amdgcn_mfma_f32_16x16x32_bf16(ql[mt][kk], kf_h[nt], sc[mt][nt], 0, 0, 0);
        }
    }

    // ---- static-max softmax: p = exp(s - M), partial l; P -> per-wave LDS
    #pragma unroll
    for (int mt = 0; mt < 4; mt++)
      #pragma unroll
      for (int r = 0; r < 4; r++) {
        int prow = w64 + (mt << 4) + (quad << 2) + r;
        float p0 = __expf(sc[mt][0][r] - Mb[mt][r]);
        float p1 = __expf(sc[mt][1][r] - Mb[mt][r]);
        PF[prow][l16] = p0;
        PF[prow][16 + l16] = p1;
        lsum[mt][r] += p0 + p1;
      }
    // no barrier: each wave reads only its own P rows (RAW via lgkmcnt)

    // ---- O += P V (V-frags hoisted over mt; single kk since KV=32) ----
    short8v vh[4], vl[4];
    #pragma unroll
    for (int nt = 0; nt < 4; nt++) {
      vh[nt] = *(const short8v*)&VHs[(nt << 4) + l16][quad << 3];
      vl[nt] = *(const short8v*)&VLs[(nt << 4) + l16][quad << 3];
    }
    #pragma unroll
    for (int mt = 0; mt < 4; mt++) {
      const float* prp = &PF[w64 + (mt << 4) + l16][quad << 3];
      float4v pa = *(const float4v*)prp;
      float4v pb = *(const float4v*)(prp + 4);
      short8v ph, pl;
      #pragma unroll
      for (int j = 0; j < 4; j++) {
        unsigned ua = __float_as_uint(pa[j]);
        unsigned ub = __float_as_uint(pb[j]);
        float la = pa[j] - __uint_as_float(ua & 0xffff0000u);
        float lb = pb[j] - __uint_as_float(ub & 0xffff0000u);
        ph[j]     = (short)(ua >> 16);
        ph[4 + j] = (short)(ub >> 16);
        pl[j]     = (short)(__float_as_uint(la) >> 16);
        pl[4 + j] = (short)(__float_as_uint(lb) >> 16);
      }
      #pragma unroll
      for (int nt = 0; nt < 4; nt++) {
        oacc[mt][nt] = __builtin_amdgcn_mfma_f32_16x16x32_bf16(ph, vh[nt], oacc[mt][nt], 0, 0, 0);
        oacc[mt][nt] = __builtin_amdgcn_mfma_f32_16x16x32_bf16(ph, vl[nt], oacc[mt][nt], 0, 0, 0);
        oacc[mt][nt] = __builtin_amdgcn_mfma_f32_16x16x32_bf16(pl, vh[nt], oacc[mt][nt], 0, 0, 0);
      }
    }
  }

  // ---- one l-reduction over the 16 l16 lanes ----
  #pragma unroll
  for (int mt = 0; mt < 4; mt++)
    #pragma unroll
    for (int r = 0; r < 4; r++) {
      float l = lsum[mt][r];
      #pragma unroll
      for (int o = 8; o >= 1; o >>= 1) l += __shfl_xor(l, o);
      lsum[mt][r] = l;
    }

  // ---- epilogue: o = O/l, split hi/lo, write [b][s][h][hd] ----
  #pragma unroll
  for (int mt = 0; mt < 4; mt++)
    #pragma unroll
    for (int r = 0; r < 4; r++) {
      float invl = 1.0f / lsum[mt][r];
      int srow = q0 + w64 + (mt << 4) + (quad << 2) + r;
      u64 gbase = ((u64)(b * Sdim + srow) * Hdim + h) * HDdim;
      #pragma unroll
      for (int nt = 0; nt < 4; nt++) {
        float o = oacc[mt][nt][r] * invl;
        ushort_t t = f2bf(o);
        OHI[gbase + (nt << 4) + l16] = t;
        OLO[gbase + (nt << 4) + l16] = f2bf(o - bf2f(t));
      }
    }
}

// ---------------------------------------------------------------------------
// elementwise stages
// ---------------------------------------------------------------------------
__global__ __launch_bounds__(256) void add_qdq_kernel(
    const float* __restrict__ a, const float* __restrict__ amaxA,
    const float* __restrict__ x, float* __restrict__ outp, u64 n,
    float* __restrict__ amaxOut)
{
  const float aA = *amaxA;
  u64 i = (u64)blockIdx.x * 256 + threadIdx.x;
  u64 stride = (u64)gridDim.x * 256;
  float m = 0.0f;
  for (; i < n; i += stride) {
    float t = qdq_f(a[i], aA) + x[i];
    outp[i] = t;
    m = fmaxf(m, fabsf(t));
  }
  m = blockMax256(m);
  if (threadIdx.x == 0) atomicMaxF(amaxOut, m);
}

__global__ __launch_bounds__(256) void qdq_out_kernel(
    const float* __restrict__ u, const float* __restrict__ amaxU,
    float* __restrict__ o, u64 n)
{
  const float aU = *amaxU;
  u64 i = (u64)blockIdx.x * 256 + threadIdx.x;
  u64 stride = (u64)gridDim.x * 256;
  for (; i < n; i += stride) o[i] = qdq_f(u[i], aU);
}

// ---------------------------------------------------------------------------
// launch
// ---------------------------------------------------------------------------
extern "C" void kernel_launch(void* const* d_in, const int* in_sizes, int n_in,
                              void* d_out, int out_size, void* d_ws, size_t ws_size,
                              hipStream_t stream)
{
  const float* x   = (const float*)d_in[0];
  const float* g1  = (const float*)d_in[1];
  const float* bn1 = (const float*)d_in[2];
  const float* Wq  = (const float*)d_in[3];
  const float* bq  = (const float*)d_in[4];
  const float* Wk  = (const float*)d_in[5];
  const float* bk  = (const float*)d_in[6];
  const float* Wv  = (const float*)d_in[7];
  const float* bv  = (const float*)d_in[8];
  const float* Wo  = (const float*)d_in[9];
  const float* bo  = (const float*)d_in[10];
  const float* g2  = (const float*)d_in[11];
  const float* bn2 = (const float*)d_in[12];
  const float* W1  = (const float*)d_in[13];
  const float* bf1 = (const float*)d_in[14];
  const float* W2  = (const float*)d_in[15];
  const float* bf2 = (const float*)d_in[16];
  float* out = (float*)d_out;

  const u64 NBSD = (u64)Bdim * Sdim * Ddim;     // 8,388,608
  const u64 NB4  = NBSD * 4;
  const u64 DD   = (u64)Ddim * Ddim;

  char* Wb = (char*)d_ws;
  float*       Sc   = (float*)Wb;                // 0-11 scales, 128.. KMX[64]
  float*       U0   = (float*)(Wb + 1024);
  float*       U1   = (float*)(Wb + 1024 + NB4);
  float*       F    = (float*)(Wb + 1024 + 2 * NB4);
  signed char* A8   = (signed char*)(Wb + 1024 + 6 * NB4);
  signed char* Wq8  = A8 + NBSD;                 // [Wq8;Wk8;Wv8] contiguous
  signed char* Wk8  = Wq8 + DD;
  signed char* Wv8  = Wk8 + DD;
  signed char* W18  = Wv8 + DD;
  signed char* W28  = W18 + 4 * DD;
  ushort_t*    WoBF = (ushort_t*)(W28 + 4 * DD);
  float*       NQ   = (float*)(WoBF + DD);       // 64*2048 floats
  float*       BQKV = NQ + (u64)64 * Sdim;       // 3072 floats
  float*       KMX  = Sc + 128;

  // overlays (lifetime-checked):
  float* QKV = U1;                                // fp32 [8192][3072] = U1,F0,F1
  float* F0  = F;                                 // o fp32 (post-Wo)
  ushort_t* QHp = (ushort_t*)(F + 2 * NBSD);      // Q hi/lo
  ushort_t* QLp = QHp + NBSD;
  ushort_t* KHp = (ushort_t*)(F + 3 * NBSD);      // K hi/lo
  ushort_t* KLp = KHp + NBSD;
  ushort_t* VTH = (ushort_t*)U0;                  // V^T hi/lo
  ushort_t* VTL = VTH + NBSD;
  ushort_t* OHI = (ushort_t*)U1;                  // attn out hi/lo (QKV dead)
  ushort_t* OLO = OHI + NBSD;
  signed char* G8 = (signed char*)U0;             // gelu int8 (VT dead by then)

  const u64 needBytes = (u64)((char*)(BQKV + 3072) - Wb);
  if (ws_size < needBytes) return;

  // scales: 0:h1 1:Wq 2:Wk 3:Wv 4:Wo 5:W1 6:W2 7:o_proj 8:t 9:h2 10:gelu 11:final
  init_kernel<<<13, 256, 0, stream>>>(Sc, bq, bk, bv, BQKV);

  ln_kernel<<<Bdim * Sdim, 256, 0, stream>>>(x, g1, bn1, nullptr, U0, Sc + 0);

  absmax6_kernel<<<3072, 256, 0, stream>>>(Wq, Wk, Wv, Wo, W1, W2, Sc);

  quant8_kernel<<<4096, 256, 0, stream>>>(U0, Sc + 0, A8, NBSD / 4);
  quantw_kernel<<<3840, 256, 0, stream>>>(Wq, Wk, Wv, Wo, W1, W2,
                                          Wq8, Wk8, Wv8, WoBF, W18, W28, Sc);

  const int M = Bdim * Sdim;                     // 8192

  // single plain QKV gemm -> fp32 [row][3072]
  dim3 gQKV(3 * Ddim / 128, M / 128);            // (24, 64)
  gemm_qkv3<<<gQKV, 256, 0, stream>>>(A8, Wq8, BQKV, QKV, Sc);

  dim3 gPrep(Sdim / 64, Bdim * Hdim);            // (32, 64)
  prep_attn<<<gPrep, 256, 0, stream>>>(QKV, QHp, QLp, KHp, KLp, VTH, VTL, NQ, KMX);

  dim3 gAttn(Sdim / 256, Bdim * Hdim);           // (8, 64) = 512 blocks
  attn_kernel<<<gAttn, 256, 0, stream>>>(QHp, QLp, KHp, KLp, VTH, VTL, NQ, KMX, OHI, OLO);

  dim3 gP(Ddim / 128, M / 128);                  // (8, 64)
  gemm_bf16_wo<<<gP, 256, 0, stream>>>(OHI, OLO, WoBF, bo, F0, M, Ddim, Ddim, Sc + 4, Sc + 7);

  // t = fq(o) + x -> U1
  add_qdq_kernel<<<4096, 256, 0, stream>>>(F0, Sc + 7, x, U1, NBSD, Sc + 8);

  ln_kernel<<<Bdim * Sdim, 256, 0, stream>>>(U1, g2, bn2, Sc + 8, U0, Sc + 9);
  quant8_kernel<<<4096, 256, 0, stream>>>(U0, Sc + 9, A8, NBSD / 4);

  dim3 gF1(4 * Ddim / 128, M / 128);             // (32, 64)
  gemm_i8<1><<<gF1, 256, 0, stream>>>(A8, W18, bf1, F, M, 4 * Ddim, Ddim, Sc + 9, Sc + 5, Sc + 10);

  quant8_kernel<<<4096, 256, 0, stream>>>(F, Sc + 10, G8, NBSD);

  // FFN2 with fused residual: u = acc*s + bias + qdq(t) -> d_out, amax Sc11
  gemm_i8<2><<<gP, 256, 0, stream>>>(G8, W28, bf2, out, M, Ddim, 4 * Ddim,
                                     Sc + 10, Sc + 6, Sc + 11, U1, Sc + 8);

  qdq_out_kernel<<<4096, 256, 0, stream>>>(out, Sc + 11, out, NBSD);
}

// Round 10
// 1096.672 us; speedup vs baseline: 1.0295x; 1.0295x over previous
//
#include <hip/hip_runtime.h>
#include <math.h>

#define Bdim 4
#define Sdim 2048
#define Ddim 1024
#define Hdim 16
#define HDdim 64

typedef unsigned long long u64;
typedef unsigned short ushort_t;
typedef int int4v __attribute__((ext_vector_type(4)));
typedef short short8v __attribute__((ext_vector_type(8)));
typedef float float4v __attribute__((ext_vector_type(4)));
typedef unsigned short us4v __attribute__((ext_vector_type(4)));

// ---------------------------------------------------------------------------
// helpers
// ---------------------------------------------------------------------------
__device__ __forceinline__ float qdq_f(float x, float amax) {
  float s = fmaxf(amax / 127.0f, 1e-8f);
  float r = rintf(x / s);                 // exact-division path (residual-visible)
  r = fminf(fmaxf(r, -128.0f), 127.0f);
  return r * s;
}

__device__ __forceinline__ void atomicMaxF(float* a, float v) {
  atomicMax((int*)a, __float_as_int(v));   // valid: non-negative floats
}

__device__ __forceinline__ float blockMax256(float v) {
  __shared__ float sred[4];
  #pragma unroll
  for (int o = 32; o > 0; o >>= 1) v = fmaxf(v, __shfl_xor(v, o));
  if ((threadIdx.x & 63) == 0) sred[threadIdx.x >> 6] = v;
  __syncthreads();
  return fmaxf(fmaxf(sred[0], sred[1]), fmaxf(sred[2], sred[3]));
}

__device__ __forceinline__ ushort_t f2bf(float f) {  // RNE fp32->bf16
  unsigned u = __float_as_uint(f);
  return (ushort_t)((u + 0x7FFFu + ((u >> 16) & 1u)) >> 16);
}
__device__ __forceinline__ float bf2f(ushort_t h) {
  return __uint_as_float(((unsigned)h) << 16);
}

// blk 0: zero scalars; blk 1..12: concat [bq;bk;bv] -> BQKV
__global__ void init_kernel(float* __restrict__ s,
                            const float* __restrict__ bq, const float* __restrict__ bk,
                            const float* __restrict__ bv, float* __restrict__ o) {
  if (blockIdx.x == 0) { s[threadIdx.x] = 0.0f; return; }
  int t = (blockIdx.x - 1) * 256 + threadIdx.x;   // 0..3071
  o[t] = (t < 1024) ? bq[t] : (t < 2048) ? bk[t - 1024] : bv[t - 2048];
}

// ---------------------------------------------------------------------------
// merged absmax of 6 weights (segmented grid-stride)
// ---------------------------------------------------------------------------
__global__ __launch_bounds__(256) void absmax6_kernel(
    const float* __restrict__ Wq, const float* __restrict__ Wk,
    const float* __restrict__ Wv, const float* __restrict__ Wo,
    const float* __restrict__ W1, const float* __restrict__ W2,
    float* __restrict__ Sc)
{
  const u64 DD = (u64)Ddim * Ddim;
  int blk = blockIdx.x;
  const float* src; float* dst; u64 lb, nb, n;
  if (blk < 256)       { src = Wq; dst = Sc + 1; lb = blk;        nb = 256;  n = DD; }
  else if (blk < 512)  { src = Wk; dst = Sc + 2; lb = blk - 256;  nb = 256;  n = DD; }
  else if (blk < 768)  { src = Wv; dst = Sc + 3; lb = blk - 512;  nb = 256;  n = DD; }
  else if (blk < 1024) { src = Wo; dst = Sc + 4; lb = blk - 768;  nb = 256;  n = DD; }
  else if (blk < 2048) { src = W1; dst = Sc + 5; lb = blk - 1024; nb = 1024; n = 4 * DD; }
  else                 { src = W2; dst = Sc + 6; lb = blk - 2048; nb = 1024; n = 4 * DD; }
  u64 i = lb * 256 + threadIdx.x;
  u64 stride = nb * 256;
  float m = 0.0f;
  for (; i < n; i += stride) m = fmaxf(m, fabsf(src[i]));
  m = blockMax256(m);
  if (threadIdx.x == 0) atomicMaxF(dst, m);
}

// ---------------------------------------------------------------------------
// merged weight quantization: Wq/Wk/Wv/W1/W2 -> int8, Wo -> int-in-bf16
// ---------------------------------------------------------------------------
__global__ __launch_bounds__(256) void quantw_kernel(
    const float* __restrict__ Wq, const float* __restrict__ Wk,
    const float* __restrict__ Wv, const float* __restrict__ Wo,
    const float* __restrict__ W1, const float* __restrict__ W2,
    signed char* __restrict__ Wq8, signed char* __restrict__ Wk8,
    signed char* __restrict__ Wv8, ushort_t* __restrict__ WoBF,
    signed char* __restrict__ W18, signed char* __restrict__ W28,
    const float* __restrict__ Sc)
{
  const u64 DD = (u64)Ddim * Ddim;
  int blk = blockIdx.x;
  if (blk < 2816) {   // int8 path (float4 units)
    const float* src; signed char* dst; float sa; u64 lb, nb, n4;
    if (blk < 256)       { src = Wq; dst = Wq8; sa = Sc[1]; lb = blk;        nb = 256;  n4 = DD / 4; }
    else if (blk < 512)  { src = Wk; dst = Wk8; sa = Sc[2]; lb = blk - 256;  nb = 256;  n4 = DD / 4; }
    else if (blk < 768)  { src = Wv; dst = Wv8; sa = Sc[3]; lb = blk - 512;  nb = 256;  n4 = DD / 4; }
    else if (blk < 1792) { src = W1; dst = W18; sa = Sc[5]; lb = blk - 768;  nb = 1024; n4 = DD; }
    else                 { src = W2; dst = W28; sa = Sc[6]; lb = blk - 1792; nb = 1024; n4 = DD; }
    const float is = 1.0f / fmaxf(sa / 127.0f, 1e-8f);
    u64 i = lb * 256 + threadIdx.x;
    u64 stride = nb * 256;
    for (; i < n4; i += stride) {
      float4 v = ((const float4*)src)[i];
      int b0 = (int)fminf(fmaxf(rintf(v.x * is), -128.0f), 127.0f) & 255;
      int b1 = (int)fminf(fmaxf(rintf(v.y * is), -128.0f), 127.0f) & 255;
      int b2 = (int)fminf(fmaxf(rintf(v.z * is), -128.0f), 127.0f) & 255;
      int b3 = (int)fminf(fmaxf(rintf(v.w * is), -128.0f), 127.0f) & 255;
      ((unsigned*)dst)[i] = (unsigned)(b0 | (b1 << 8) | (b2 << 16) | (b3 << 24));
    }
  } else {            // Wo -> exact int in bf16
    const float is = 1.0f / fmaxf(Sc[4] / 127.0f, 1e-8f);
    u64 i = (u64)(blk - 2816) * 256 + threadIdx.x;
    u64 stride = 1024ull * 256;
    for (; i < DD; i += stride) {
      float r = fminf(fmaxf(rintf(Wo[i] * is), -128.0f), 127.0f);
      WoBF[i] = f2bf(r);
    }
  }
}

// ---------------------------------------------------------------------------
// quantize fp32 -> int8 (packed 4/thread) — activations feeding GEMMs
// ---------------------------------------------------------------------------
__global__ __launch_bounds__(256) void quant8_kernel(
    const float* __restrict__ x, const float* __restrict__ amaxp,
    signed char* __restrict__ q, u64 n4)
{
  const float is = 1.0f / fmaxf(*amaxp / 127.0f, 1e-8f);
  u64 i = (u64)blockIdx.x * 256 + threadIdx.x;
  u64 stride = (u64)gridDim.x * 256;
  for (; i < n4; i += stride) {
    float4 v = ((const float4*)x)[i];
    int b0 = (int)fminf(fmaxf(rintf(v.x * is), -128.0f), 127.0f) & 255;
    int b1 = (int)fminf(fmaxf(rintf(v.y * is), -128.0f), 127.0f) & 255;
    int b2 = (int)fminf(fmaxf(rintf(v.z * is), -128.0f), 127.0f) & 255;
    int b3 = (int)fminf(fmaxf(rintf(v.w * is), -128.0f), 127.0f) & 255;
    ((unsigned*)q)[i] = (unsigned)(b0 | (b1 << 8) | (b2 << 16) | (b3 << 24));
  }
}

// ---------------------------------------------------------------------------
// LayerNorm (one block per row of 1024), optional input qdq, output absmax
// ---------------------------------------------------------------------------
__global__ __launch_bounds__(256) void ln_kernel(
    const float* __restrict__ x, const float* __restrict__ g,
    const float* __restrict__ beta, const float* __restrict__ inAmax,
    float* __restrict__ y, float* __restrict__ amaxOut)
{
  __shared__ float sred[4];
  __shared__ float smv[2];
  const int tid = threadIdx.x;
  const u64 row = blockIdx.x;
  const float* xr = x + row * Ddim;
  float* yr = y + row * Ddim;
  float aIn = inAmax ? *inAmax : 0.0f;

  float vals[4];
  float sum = 0.0f;
  #pragma unroll
  for (int i = 0; i < 4; i++) {
    float v = xr[tid + (i << 8)];
    if (inAmax) v = qdq_f(v, aIn);
    vals[i] = v;
    sum += v;
  }
  #pragma unroll
  for (int o = 32; o > 0; o >>= 1) sum += __shfl_xor(sum, o);
  if ((tid & 63) == 0) sred[tid >> 6] = sum;
  __syncthreads();
  if (tid == 0) smv[0] = (sred[0] + sred[1] + sred[2] + sred[3]) * (1.0f / 1024.0f);
  __syncthreads();
  const float mean = smv[0];

  float dev = 0.0f;
  #pragma unroll
  for (int i = 0; i < 4; i++) { float d = vals[i] - mean; dev += d * d; }
  #pragma unroll
  for (int o = 32; o > 0; o >>= 1) dev += __shfl_xor(dev, o);
  if ((tid & 63) == 0) sred[tid >> 6] = dev;
  __syncthreads();
  if (tid == 0) {
    float var = (sred[0] + sred[1] + sred[2] + sred[3]) * (1.0f / 1024.0f);
    smv[1] = 1.0f / sqrtf(var + 1e-5f);
  }
  __syncthreads();
  const float inv = smv[1];

  float lmax = 0.0f;
  #pragma unroll
  for (int i = 0; i < 4; i++) {
    int c = tid + (i << 8);
    float ov = (vals[i] - mean) * inv * g[c] + beta[c];
    yr[c] = ov;
    lmax = fmaxf(lmax, fabsf(ov));
  }
  #pragma unroll
  for (int o = 32; o > 0; o >>= 1) lmax = fmaxf(lmax, __shfl_xor(lmax, o));
  __syncthreads();
  if ((tid & 63) == 0) sred[tid >> 6] = lmax;
  __syncthreads();
  if (tid == 0)
    atomicMaxF(amaxOut, fmaxf(fmaxf(sred[0], sred[1]), fmaxf(sred[2], sred[3])));
}

// ---------------------------------------------------------------------------
// i8 MFMA GEMM: C[M,N] = (A8[M,K] @ B8[N,K]^T)*sA*sB + bias[N]
// 128x128 tile, BK=64, 2x2 waves x 4x4 mfma_i32_16x16x64_i8 tiles.
// EPI: 0 none; 1 gelu+amax; 2 +qdq(T)+amax (fused residual add)
// ---------------------------------------------------------------------------
template <int EPI>
__global__ __launch_bounds__(256) void gemm_i8(
    const signed char* __restrict__ A8, const signed char* __restrict__ B8,
    const float* __restrict__ bias, float* __restrict__ C,
    int M, int N, int K,
    const float* __restrict__ sAp, const float* __restrict__ sBp,
    float* __restrict__ amaxOut,
    const float* __restrict__ Tm = nullptr,
    const float* __restrict__ amaxT = nullptr)
{
  __shared__ __align__(16) signed char As[128][80];
  __shared__ __align__(16) signed char Bs[128][80];
  const int tid = threadIdx.x;
  const int wave = tid >> 6, lane = tid & 63;
  const int quad = lane >> 4, l16 = lane & 15;
  const int wy = wave >> 1, wx = wave & 1;
  const int m0 = blockIdx.y << 7, n0 = blockIdx.x << 7;
  const float sA = fmaxf(*sAp / 127.0f, 1e-8f);
  const float sB = fmaxf(*sBp / 127.0f, 1e-8f);
  const float sAB = sA * sB;
  const float aT = (EPI == 2) ? *amaxT : 0.0f;

  const int sr = tid >> 2;            // staging row 0..63
  const int sc = (tid & 3) << 4;      // staging byte col 0/16/32/48

  int4v acc[4][4] = {};
  for (int k0 = 0; k0 < K; k0 += 64) {
    #pragma unroll
    for (int p = 0; p < 2; p++) {
      int r = sr + (p << 6);
      uint4 av = *(const uint4*)&A8[(u64)(m0 + r) * K + k0 + sc];
      uint4 bv = *(const uint4*)&B8[(u64)(n0 + r) * K + k0 + sc];
      *(uint4*)&As[r][sc] = av;
      *(uint4*)&Bs[r][sc] = bv;
    }
    __syncthreads();
    int4v af[4], bf[4];
    #pragma unroll
    for (int mt = 0; mt < 4; mt++)
      af[mt] = *(const int4v*)&As[(wy << 6) + (mt << 4) + l16][quad << 4];
    #pragma unroll
    for (int nt = 0; nt < 4; nt++)
      bf[nt] = *(const int4v*)&Bs[(wx << 6) + (nt << 4) + l16][quad << 4];
    #pragma unroll
    for (int mt = 0; mt < 4; mt++)
      #pragma unroll
      for (int nt = 0; nt < 4; nt++)
        acc[mt][nt] = __builtin_amdgcn_mfma_i32_16x16x64_i8(af[mt], bf[nt], acc[mt][nt], 0, 0, 0);
    __syncthreads();
  }

  float lmax = 0.0f;
  #pragma unroll
  for (int mt = 0; mt < 4; mt++) {
    #pragma unroll
    for (int reg = 0; reg < 4; reg++) {
      int row = m0 + (wy << 6) + (mt << 4) + (quad << 2) + reg;
      #pragma unroll
      for (int nt = 0; nt < 4; nt++) {
        int col = n0 + (wx << 6) + (nt << 4) + l16;
        float v = (float)acc[mt][nt][reg] * sAB + bias[col];
        if (EPI == 1) {
          v = 0.5f * v * (1.0f + erff(v * 0.70710678118654752440f));
          lmax = fmaxf(lmax, fabsf(v));
        }
        if (EPI == 2) {
          v += qdq_f(Tm[(u64)row * N + col], aT);
          lmax = fmaxf(lmax, fabsf(v));
        }
        C[(u64)row * N + col] = v;
      }
    }
  }
  if (EPI >= 1) {
    lmax = blockMax256(lmax);
    if (tid == 0) atomicMaxF(amaxOut, lmax);
  }
}

// ---------------------------------------------------------------------------
// plain mega-QKV i8 GEMM: C[M,3072] = A8 @ [Wq8;Wk8;Wv8]^T + BQKV
// per-segment weight scale (seg = n0>>10). Epilogue = store only (no
// transcendentals -> no libcall spills; see R7 post-mortem).
// ---------------------------------------------------------------------------
__global__ __launch_bounds__(256) void gemm_qkv3(
    const signed char* __restrict__ A8, const signed char* __restrict__ B8,
    const float* __restrict__ bias, float* __restrict__ C,
    const float* __restrict__ Sc)
{
  __shared__ __align__(16) signed char As[128][80];
  __shared__ __align__(16) signed char Bs[128][80];
  const int tid = threadIdx.x;
  const int wave = tid >> 6, lane = tid & 63;
  const int quad = lane >> 4, l16 = lane & 15;
  const int wy = wave >> 1, wx = wave & 1;
  const int m0 = blockIdx.y << 7, n0 = blockIdx.x << 7;
  const int K = Ddim, N = 3 * Ddim;
  const int seg = n0 >> 10;
  const float sA = fmaxf(Sc[0] / 127.0f, 1e-8f);
  const float sB = fmaxf(Sc[1 + seg] / 127.0f, 1e-8f);
  const float sAB = sA * sB;

  const int sr = tid >> 2;
  const int sc_ = (tid & 3) << 4;

  int4v acc[4][4] = {};
  for (int k0 = 0; k0 < K; k0 += 64) {
    #pragma unroll
    for (int p = 0; p < 2; p++) {
      int r = sr + (p << 6);
      uint4 av = *(const uint4*)&A8[(u64)(m0 + r) * K + k0 + sc_];
      uint4 bv = *(const uint4*)&B8[(u64)(n0 + r) * K + k0 + sc_];
      *(uint4*)&As[r][sc_] = av;
      *(uint4*)&Bs[r][sc_] = bv;
    }
    __syncthreads();
    int4v af[4], bf[4];
    #pragma unroll
    for (int mt = 0; mt < 4; mt++)
      af[mt] = *(const int4v*)&As[(wy << 6) + (mt << 4) + l16][quad << 4];
    #pragma unroll
    for (int nt = 0; nt < 4; nt++)
      bf[nt] = *(const int4v*)&Bs[(wx << 6) + (nt << 4) + l16][quad << 4];
    #pragma unroll
    for (int mt = 0; mt < 4; mt++)
      #pragma unroll
      for (int nt = 0; nt < 4; nt++)
        acc[mt][nt] = __builtin_amdgcn_mfma_i32_16x16x64_i8(af[mt], bf[nt], acc[mt][nt], 0, 0, 0);
    __syncthreads();
  }

  #pragma unroll
  for (int mt = 0; mt < 4; mt++) {
    #pragma unroll
    for (int reg = 0; reg < 4; reg++) {
      int row = m0 + (wy << 6) + (mt << 4) + (quad << 2) + reg;
      #pragma unroll
      for (int nt = 0; nt < 4; nt++) {
        int col = n0 + (wx << 6) + (nt << 4) + l16;
        C[(u64)row * N + col] = (float)acc[mt][nt][reg] * sAB + bias[col];
      }
    }
  }
}

// ---------------------------------------------------------------------------
// bf16-split MFMA GEMM for Wo: C = ((Ahi+Alo)[M,K] @ Wq[N,K]^T)*sW + bias
// ---------------------------------------------------------------------------
__global__ __launch_bounds__(256) void gemm_bf16_wo(
    const ushort_t* __restrict__ Ahi, const ushort_t* __restrict__ Alo,
    const ushort_t* __restrict__ Bw, const float* __restrict__ bias,
    float* __restrict__ C, int M, int N, int K,
    const float* __restrict__ sWp, float* __restrict__ amaxOut)
{
  __shared__ __align__(16) ushort_t Hs[128][40];
  __shared__ __align__(16) ushort_t Ls[128][40];
  __shared__ __align__(16) ushort_t Ws[128][40];
  const int tid = threadIdx.x;
  const int wave = tid >> 6, lane = tid & 63;
  const int quad = lane >> 4, l16 = lane & 15;
  const int wy = wave >> 1, wx = wave & 1;
  const int m0 = blockIdx.y << 7, n0 = blockIdx.x << 7;
  const float sW = fmaxf(*sWp / 127.0f, 1e-8f);

  const int sr = tid >> 2;
  const int sce = (tid & 3) << 3;

  float4v acc[4][4] = {};
  for (int k0 = 0; k0 < K; k0 += 32) {
    #pragma unroll
    for (int p = 0; p < 2; p++) {
      int r = sr + (p << 6);
      uint4 hv = *(const uint4*)&Ahi[(u64)(m0 + r) * K + k0 + sce];
      uint4 lv = *(const uint4*)&Alo[(u64)(m0 + r) * K + k0 + sce];
      uint4 wv = *(const uint4*)&Bw[(u64)(n0 + r) * K + k0 + sce];
      *(uint4*)&Hs[r][sce] = hv;
      *(uint4*)&Ls[r][sce] = lv;
      *(uint4*)&Ws[r][sce] = wv;
    }
    __syncthreads();
    short8v ah[4], al[4], bw[4];
    #pragma unroll
    for (int mt = 0; mt < 4; mt++) {
      ah[mt] = *(const short8v*)&Hs[(wy << 6) + (mt << 4) + l16][quad << 3];
      al[mt] = *(const short8v*)&Ls[(wy << 6) + (mt << 4) + l16][quad << 3];
    }
    #pragma unroll
    for (int nt = 0; nt < 4; nt++)
      bw[nt] = *(const short8v*)&Ws[(wx << 6) + (nt << 4) + l16][quad << 3];
    #pragma unroll
    for (int mt = 0; mt < 4; mt++)
      #pragma unroll
      for (int nt = 0; nt < 4; nt++) {
        acc[mt][nt] = __builtin_amdgcn_mfma_f32_16x16x32_bf16(ah[mt], bw[nt], acc[mt][nt], 0, 0, 0);
        acc[mt][nt] = __builtin_amdgcn_mfma_f32_16x16x32_bf16(al[mt], bw[nt], acc[mt][nt], 0, 0, 0);
      }
    __syncthreads();
  }

  float lmax = 0.0f;
  #pragma unroll
  for (int mt = 0; mt < 4; mt++) {
    #pragma unroll
    for (int reg = 0; reg < 4; reg++) {
      int row = m0 + (wy << 6) + (mt << 4) + (quad << 2) + reg;
      #pragma unroll
      for (int nt = 0; nt < 4; nt++) {
        int col = n0 + (wx << 6) + (nt << 4) + l16;
        float v = acc[mt][nt][reg] * sW + bias[col];
        lmax = fmaxf(lmax, fabsf(v));
        C[(u64)row * N + col] = v;
      }
    }
  }
  lmax = blockMax256(lmax);
  if (tid == 0) atomicMaxF(amaxOut, lmax);
}

// ---------------------------------------------------------------------------
// prep_attn: rope(q)*0.125, rope(k), hi/lo bf16 split, V transpose, norms.
// In:  QKV fp32 [row][3072] (cols 0..1023 q, 1024..2047 k, 2048..3071 v)
// Out: QH/QL/KH/KL ushort [bh][s][hd];  VTH/VTL ushort [bh][hd][s]
// grid (S/64, B*H), block 256. (memory-bound; libcalls harmless here — R7)
// ---------------------------------------------------------------------------
__global__ __launch_bounds__(256) void prep_attn(
    const float* __restrict__ QKV,
    ushort_t* __restrict__ QH, ushort_t* __restrict__ QL,
    ushort_t* __restrict__ KH, ushort_t* __restrict__ KL,
    ushort_t* __restrict__ VTH, ushort_t* __restrict__ VTL,
    float* __restrict__ NQ, float* __restrict__ KMX)
{
  const int bh = blockIdx.y;
  const int b = bh >> 4, h = bh & 15;
  const int s0 = blockIdx.x << 6;
  const int tid = threadIdx.x;
  float kml = 0.0f;

  // --- q/k rope + scale + split + norms (2048 pairs) ---
  #pragma unroll
  for (int i = 0; i < 8; i++) {
    int idx = tid + (i << 8);          // 0..2047
    int s = idx >> 5, hp = idx & 31;
    int sa = s0 + s;
    u64 gin = (u64)(b * Sdim + sa) * 3072 + (h << 6) + hp;
    float inv = powf(10000.0f, -(float)hp * (1.0f / 32.0f));
    float ang = (float)sa * inv;
    float cs = cosf(ang), sn = sinf(ang);
    float q1 = QKV[gin],        q2 = QKV[gin + 32];
    float k1 = QKV[gin + 1024], k2 = QKV[gin + 1056];
    float qo1 = (q1 * cs - q2 * sn) * 0.125f;
    float qo2 = (q1 * sn + q2 * cs) * 0.125f;
    float ko1 = k1 * cs - k2 * sn;
    float ko2 = k1 * sn + k2 * cs;
    u64 go = ((u64)bh * Sdim + sa) * HDdim + hp;
    ushort_t t;
    t = f2bf(qo1); QH[go]      = t; QL[go]      = f2bf(qo1 - bf2f(t));
    t = f2bf(qo2); QH[go + 32] = t; QL[go + 32] = f2bf(qo2 - bf2f(t));
    t = f2bf(ko1); KH[go]      = t; KL[go]      = f2bf(ko1 - bf2f(t));
    t = f2bf(ko2); KH[go + 32] = t; KL[go + 32] = f2bf(ko2 - bf2f(t));
    float nq2 = qo1 * qo1 + qo2 * qo2;
    float nk2 = ko1 * ko1 + ko2 * ko2;
    #pragma unroll
    for (int o = 16; o >= 1; o >>= 1) {
      nq2 += __shfl_xor(nq2, o);
      nk2 += __shfl_xor(nk2, o);
    }
    if (hp == 0) {
      NQ[(u64)bh * Sdim + sa] = sqrtf(nq2);
      kml = fmaxf(kml, sqrtf(nk2));
    }
  }
  kml = blockMax256(kml);
  if (tid == 0) atomicMaxF(&KMX[bh], kml);

  // --- v: split + transpose via LDS ---
  __shared__ ushort_t VHs[64][66], VLs[64][66];
  #pragma unroll
  for (int i = 0; i < 4; i++) {
    int idx4 = tid + (i << 8);         // 0..1023
    int s = idx4 >> 4, c4 = (idx4 & 15) << 2;
    u64 gin = (u64)(b * Sdim + s0 + s) * 3072 + 2048 + (h << 6) + c4;
    float4 vv = *(const float4*)&QKV[gin];
    float va[4] = {vv.x, vv.y, vv.z, vv.w};
    #pragma unroll
    for (int j = 0; j < 4; j++) {
      ushort_t vh = f2bf(va[j]);
      VHs[s][c4 + j] = vh;
      VLs[s][c4 + j] = f2bf(va[j] - bf2f(vh));
    }
  }
  __syncthreads();
  #pragma unroll
  for (int i = 0; i < 4; i++) {
    int idx4 = tid + (i << 8);
    int hd = idx4 >> 4, s4 = (idx4 & 15) << 2;
    us4v oh, ol;
    #pragma unroll
    for (int j = 0; j < 4; j++) { oh[j] = VHs[s4 + j][hd]; ol[j] = VLs[s4 + j][hd]; }
    u64 go = ((u64)bh * HDdim + hd) * Sdim + s0 + s4;
    *(us4v*)&VTH[go] = oh;
    *(us4v*)&VTL[go] = ol;
  }
}

// ---------------------------------------------------------------------------
// MFMA flash attention v3 + XCD swizzle: static-max softmax, P fp32 in LDS,
// V-frags hoisted. Block = 128 q-rows, 4 waves x 32 (mt=2 — the VGPR+AGPR
// sweet spot, R9 lesson: mt=4 halves occupancy on the unified reg file).
// XCD swizzle: all 16 q-chunk blocks of one (b,h) share id%8 -> same XCD L2
// caches that head's K/V once (speed-only heuristic, G16-safe).
// LDS = 71680 -> 2 blocks/CU.
// ---------------------------------------------------------------------------
__global__ __launch_bounds__(256) void attn_kernel(
    const ushort_t* __restrict__ QH, const ushort_t* __restrict__ QL,
    const ushort_t* __restrict__ KH, const ushort_t* __restrict__ KL,
    const ushort_t* __restrict__ VTH, const ushort_t* __restrict__ VTL,
    const float* __restrict__ NQ, const float* __restrict__ KMX,
    ushort_t* __restrict__ OHI, ushort_t* __restrict__ OLO)
{
  __shared__ __align__(16) ushort_t KHs[64][72], KLs[64][72];
  __shared__ __align__(16) ushort_t VHs[64][72], VLs[64][72];
  __shared__ __align__(16) float PF[128][68];
  const int tid = threadIdx.x;
  const int wave = tid >> 6, lane = tid & 63;
  const int quad = lane >> 4, l16 = lane & 15;
  const int w32 = wave << 5;
  // XCD swizzle: id in [0,1024); xcd = id&7; bh = (id>>7)*8 + xcd; j = (id>>3)&15
  const int id = blockIdx.y * 16 + blockIdx.x;
  const int bh = ((id >> 7) << 3) + (id & 7);
  const int b = bh >> 4, h = bh & 15;
  const int q0 = ((id >> 3) & 15) << 7;
  const u64 bhS = (u64)bh * Sdim;

  short8v qh[2][2], ql[2][2];
  #pragma unroll
  for (int mt = 0; mt < 2; mt++)
    #pragma unroll
    for (int kk = 0; kk < 2; kk++) {
      u64 g = (bhS + q0 + w32 + (mt << 4) + l16) * HDdim + (kk << 5) + (quad << 3);
      qh[mt][kk] = *(const short8v*)&QH[g];
      ql[mt][kk] = *(const short8v*)&QL[g];
    }

  const float kmax = KMX[bh] * 1.0009765625f;
  float Mb[2][4], lsum[2][4];
  #pragma unroll
  for (int mt = 0; mt < 2; mt++)
    #pragma unroll
    for (int r = 0; r < 4; r++) {
      Mb[mt][r] = NQ[bhS + q0 + w32 + (mt << 4) + (quad << 2) + r] * kmax;
      lsum[mt][r] = 0.0f;
    }

  float4v oacc[2][4] = {};

  for (int j0 = 0; j0 < Sdim; j0 += 64) {
    __syncthreads();
    #pragma unroll
    for (int i = 0; i < 2; i++) {
      int idx = tid + (i << 8);
      int r = idx >> 3, c8 = (idx & 7) << 3;
      u64 gk = (bhS + j0 + r) * HDdim + c8;
      *(uint4*)&KHs[r][c8] = *(const uint4*)&KH[gk];
      *(uint4*)&KLs[r][c8] = *(const uint4*)&KL[gk];
      u64 gv = ((u64)bh * HDdim + r) * Sdim + j0 + c8;
      *(uint4*)&VHs[r][c8] = *(const uint4*)&VTH[gv];
      *(uint4*)&VLs[r][c8] = *(const uint4*)&VTL[gv];
    }
    __syncthreads();

    float4v sc[2][4] = {};
    #pragma unroll
    for (int kk = 0; kk < 2; kk++)
      #pragma unroll
      for (int nt = 0; nt < 4; nt++) {
        short8v bh_ = *(const short8v*)&KHs[(nt << 4) + l16][(kk << 5) + (quad << 3)];
        short8v bl_ = *(const short8v*)&KLs[(nt << 4) + l16][(kk << 5) + (quad << 3)];
        #pragma unroll
        for (int mt = 0; mt < 2; mt++) {
          sc[mt][nt] = __builtin_amdgcn_mfma_f32_16x16x32_bf16(qh[mt][kk], bh_, sc[mt][nt], 0, 0, 0);
          sc[mt][nt] = __builtin_amdgcn_mfma_f32_16x16x32_bf16(qh[mt][kk], bl_, sc[mt][nt], 0, 0, 0);
          sc[mt][nt] = __builtin_amdgcn_mfma_f32_16x16x32_bf16(ql[mt][kk], bh_, sc[mt][nt], 0, 0, 0);
        }
      }

    #pragma unroll
    for (int mt = 0; mt < 2; mt++)
      #pragma unroll
      for (int r = 0; r < 4; r++) {
        int prow = w32 + (mt << 4) + (quad << 2) + r;
        float lacc = 0.0f;
        #pragma unroll
        for (int nt = 0; nt < 4; nt++) {
          float p = __expf(sc[mt][nt][r] - Mb[mt][r]);
          lacc += p;
          PF[prow][(nt << 4) + l16] = p;
        }
        lsum[mt][r] += lacc;
      }
    // no barrier: each wave reads only its own P rows (RAW via lgkmcnt)

    #pragma unroll
    for (int kk = 0; kk < 2; kk++) {
      short8v vh[4], vl[4];
      #pragma unroll
      for (int nt = 0; nt < 4; nt++) {
        vh[nt] = *(const short8v*)&VHs[(nt << 4) + l16][(kk << 5) + (quad << 3)];
        vl[nt] = *(const short8v*)&VLs[(nt << 4) + l16][(kk << 5) + (quad << 3)];
      }
      #pragma unroll
      for (int mt = 0; mt < 2; mt++) {
        const float* prp = &PF[w32 + (mt << 4) + l16][(kk << 5) + (quad << 3)];
        float4v pa = *(const float4v*)prp;
        float4v pb = *(const float4v*)(prp + 4);
        short8v ph, pl;
        #pragma unroll
        for (int j = 0; j < 4; j++) {
          unsigned ua = __float_as_uint(pa[j]);
          unsigned ub = __float_as_uint(pb[j]);
          float la = pa[j] - __uint_as_float(ua & 0xffff0000u);
          float lb = pb[j] - __uint_as_float(ub & 0xffff0000u);
          ph[j]     = (short)(ua >> 16);
          ph[4 + j] = (short)(ub >> 16);
          pl[j]     = (short)(__float_as_uint(la) >> 16);
          pl[4 + j] = (short)(__float_as_uint(lb) >> 16);
        }
        #pragma unroll
        for (int nt = 0; nt < 4; nt++) {
          oacc[mt][nt] = __builtin_amdgcn_mfma_f32_16x16x32_bf16(ph, vh[nt], oacc[mt][nt], 0, 0, 0);
          oacc[mt][nt] = __builtin_amdgcn_mfma_f32_16x16x32_bf16(ph, vl[nt], oacc[mt][nt], 0, 0, 0);
          oacc[mt][nt] = __builtin_amdgcn_mfma_f32_16x16x32_bf16(pl, vh[nt], oacc[mt][nt], 0, 0, 0);
        }
      }
    }
  }

  #pragma unroll
  for (int mt = 0; mt < 2; mt++)
    #pragma unroll
    for (int r = 0; r < 4; r++) {
      float l = lsum[mt][r];
      #pragma unroll
      for (int o = 8; o >= 1; o >>= 1) l += __shfl_xor(l, o);
      lsum[mt][r] = l;
    }

  #pragma unroll
  for (int mt = 0; mt < 2; mt++)
    #pragma unroll
    for (int r = 0; r < 4; r++) {
      float invl = 1.0f / lsum[mt][r];
      int srow = q0 + w32 + (mt << 4) + (quad << 2) + r;
      u64 gbase = ((u64)(b * Sdim + srow) * Hdim + h) * HDdim;
      #pragma unroll
      for (int nt = 0; nt < 4; nt++) {
        float o = oacc[mt][nt][r] * invl;
        ushort_t t = f2bf(o);
        OHI[gbase + (nt << 4) + l16] = t;
        OLO[gbase + (nt << 4) + l16] = f2bf(o - bf2f(t));
      }
    }
}

// ---------------------------------------------------------------------------
// elementwise stages
// ---------------------------------------------------------------------------
__global__ __launch_bounds__(256) void add_qdq_kernel(
    const float* __restrict__ a, const float* __restrict__ amaxA,
    const float* __restrict__ x, float* __restrict__ outp, u64 n,
    float* __restrict__ amaxOut)
{
  const float aA = *amaxA;
  u64 i = (u64)blockIdx.x * 256 + threadIdx.x;
  u64 stride = (u64)gridDim.x * 256;
  float m = 0.0f;
  for (; i < n; i += stride) {
    float t = qdq_f(a[i], aA) + x[i];
    outp[i] = t;
    m = fmaxf(m, fabsf(t));
  }
  m = blockMax256(m);
  if (threadIdx.x == 0) atomicMaxF(amaxOut, m);
}

__global__ __launch_bounds__(256) void qdq_out_kernel(
    const float* __restrict__ u, const float* __restrict__ amaxU,
    float* __restrict__ o, u64 n)
{
  const float aU = *amaxU;
  u64 i = (u64)blockIdx.x * 256 + threadIdx.x;
  u64 stride = (u64)gridDim.x * 256;
  for (; i < n; i += stride) o[i] = qdq_f(u[i], aU);
}

// ---------------------------------------------------------------------------
// launch
// ---------------------------------------------------------------------------
extern "C" void kernel_launch(void* const* d_in, const int* in_sizes, int n_in,
                              void* d_out, int out_size, void* d_ws, size_t ws_size,
                              hipStream_t stream)
{
  const float* x   = (const float*)d_in[0];
  const float* g1  = (const float*)d_in[1];
  const float* bn1 = (const float*)d_in[2];
  const float* Wq  = (const float*)d_in[3];
  const float* bq  = (const float*)d_in[4];
  const float* Wk  = (const float*)d_in[5];
  const float* bk  = (const float*)d_in[6];
  const float* Wv  = (const float*)d_in[7];
  const float* bv  = (const float*)d_in[8];
  const float* Wo  = (const float*)d_in[9];
  const float* bo  = (const float*)d_in[10];
  const float* g2  = (const float*)d_in[11];
  const float* bn2 = (const float*)d_in[12];
  const float* W1  = (const float*)d_in[13];
  const float* bf1 = (const float*)d_in[14];
  const float* W2  = (const float*)d_in[15];
  const float* bf2 = (const float*)d_in[16];
  float* out = (float*)d_out;

  const u64 NBSD = (u64)Bdim * Sdim * Ddim;     // 8,388,608
  const u64 NB4  = NBSD * 4;
  const u64 DD   = (u64)Ddim * Ddim;

  char* Wb = (char*)d_ws;
  float*       Sc   = (float*)Wb;                // 0-11 scales, 128.. KMX[64]
  float*       U0   = (float*)(Wb + 1024);
  float*       U1   = (float*)(Wb + 1024 + NB4);
  float*       F    = (float*)(Wb + 1024 + 2 * NB4);
  signed char* A8   = (signed char*)(Wb + 1024 + 6 * NB4);
  signed char* Wq8  = A8 + NBSD;                 // [Wq8;Wk8;Wv8] contiguous
  signed char* Wk8  = Wq8 + DD;
  signed char* Wv8  = Wk8 + DD;
  signed char* W18  = Wv8 + DD;
  signed char* W28  = W18 + 4 * DD;
  ushort_t*    WoBF = (ushort_t*)(W28 + 4 * DD);
  float*       NQ   = (float*)(WoBF + DD);       // 64*2048 floats
  float*       BQKV = NQ + (u64)64 * Sdim;       // 3072 floats
  float*       KMX  = Sc + 128;

  // overlays (lifetime-checked):
  float* QKV = U1;                                // fp32 [8192][3072] = U1,F0,F1
  float* F0  = F;                                 // o fp32 (post-Wo)
  ushort_t* QHp = (ushort_t*)(F + 2 * NBSD);      // Q hi/lo
  ushort_t* QLp = QHp + NBSD;
  ushort_t* KHp = (ushort_t*)(F + 3 * NBSD);      // K hi/lo
  ushort_t* KLp = KHp + NBSD;
  ushort_t* VTH = (ushort_t*)U0;                  // V^T hi/lo
  ushort_t* VTL = VTH + NBSD;
  ushort_t* OHI = (ushort_t*)U1;                  // attn out hi/lo (QKV dead)
  ushort_t* OLO = OHI + NBSD;
  signed char* G8 = (signed char*)U0;             // gelu int8 (VT dead by then)

  const u64 needBytes = (u64)((char*)(BQKV + 3072) - Wb);
  if (ws_size < needBytes) return;

  // scales: 0:h1 1:Wq 2:Wk 3:Wv 4:Wo 5:W1 6:W2 7:o_proj 8:t 9:h2 10:gelu 11:final
  init_kernel<<<13, 256, 0, stream>>>(Sc, bq, bk, bv, BQKV);

  ln_kernel<<<Bdim * Sdim, 256, 0, stream>>>(x, g1, bn1, nullptr, U0, Sc + 0);

  absmax6_kernel<<<3072, 256, 0, stream>>>(Wq, Wk, Wv, Wo, W1, W2, Sc);

  quant8_kernel<<<4096, 256, 0, stream>>>(U0, Sc + 0, A8, NBSD / 4);
  quantw_kernel<<<3840, 256, 0, stream>>>(Wq, Wk, Wv, Wo, W1, W2,
                                          Wq8, Wk8, Wv8, WoBF, W18, W28, Sc);

  const int M = Bdim * Sdim;                     // 8192

  // single plain QKV gemm -> fp32 [row][3072]
  dim3 gQKV(3 * Ddim / 128, M / 128);            // (24, 64)
  gemm_qkv3<<<gQKV, 256, 0, stream>>>(A8, Wq8, BQKV, QKV, Sc);

  dim3 gPrep(Sdim / 64, Bdim * Hdim);            // (32, 64)
  prep_attn<<<gPrep, 256, 0, stream>>>(QKV, QHp, QLp, KHp, KLp, VTH, VTL, NQ, KMX);

  dim3 gAttn(Sdim / 128, Bdim * Hdim);           // (16, 64) — swizzled in-kernel
  attn_kernel<<<gAttn, 256, 0, stream>>>(QHp, QLp, KHp, KLp, VTH, VTL, NQ, KMX, OHI, OLO);

  dim3 gP(Ddim / 128, M / 128);                  // (8, 64)
  gemm_bf16_wo<<<gP, 256, 0, stream>>>(OHI, OLO, WoBF, bo, F0, M, Ddim, Ddim, Sc + 4, Sc + 7);

  // t = fq(o) + x -> U1
  add_qdq_kernel<<<4096, 256, 0, stream>>>(F0, Sc + 7, x, U1, NBSD, Sc + 8);

  ln_kernel<<<Bdim * Sdim, 256, 0, stream>>>(U1, g2, bn2, Sc + 8, U0, Sc + 9);
  quant8_kernel<<<4096, 256, 0, stream>>>(U0, Sc + 9, A8, NBSD / 4);

  dim3 gF1(4 * Ddim / 128, M / 128);             // (32, 64)
  gemm_i8<1><<<gF1, 256, 0, stream>>>(A8, W18, bf1, F, M, 4 * Ddim, Ddim, Sc + 9, Sc + 5, Sc + 10);

  quant8_kernel<<<4096, 256, 0, stream>>>(F, Sc + 10, G8, NBSD);

  // FFN2 with fused residual: u = acc*s + bias + qdq(t) -> d_out, amax Sc11
  gemm_i8<2><<<gP, 256, 0, stream>>>(G8, W28, bf2, out, M, Ddim, 4 * Ddim,
                                     Sc + 10, Sc + 6, Sc + 11, U1, Sc + 8);

  qdq_out_kernel<<<4096, 256, 0, stream>>>(out, Sc + 11, out, NBSD);
}

// Round 11
// 1010.115 us; speedup vs baseline: 1.1177x; 1.0857x over previous
//
#include <hip/hip_runtime.h>
#include <math.h>

#define Bdim 4
#define Sdim 2048
#define Ddim 1024
#define Hdim 16
#define HDdim 64

typedef unsigned long long u64;
typedef unsigned short ushort_t;
typedef int int4v __attribute__((ext_vector_type(4)));
typedef short short8v __attribute__((ext_vector_type(8)));
typedef float float4v __attribute__((ext_vector_type(4)));
typedef unsigned short us4v __attribute__((ext_vector_type(4)));

// ---------------------------------------------------------------------------
// helpers
// ---------------------------------------------------------------------------
__device__ __forceinline__ float qdq_f(float x, float amax) {
  float s = fmaxf(amax / 127.0f, 1e-8f);
  float r = rintf(x / s);                 // exact-division path (residual-visible)
  r = fminf(fmaxf(r, -128.0f), 127.0f);
  return r * s;
}

__device__ __forceinline__ void atomicMaxF(float* a, float v) {
  atomicMax((int*)a, __float_as_int(v));   // valid: non-negative floats
}

__device__ __forceinline__ float blockMax256(float v) {
  __shared__ float sred[4];
  #pragma unroll
  for (int o = 32; o > 0; o >>= 1) v = fmaxf(v, __shfl_xor(v, o));
  if ((threadIdx.x & 63) == 0) sred[threadIdx.x >> 6] = v;
  __syncthreads();
  return fmaxf(fmaxf(sred[0], sred[1]), fmaxf(sred[2], sred[3]));
}

__device__ __forceinline__ ushort_t f2bf(float f) {  // RNE fp32->bf16
  unsigned u = __float_as_uint(f);
  return (ushort_t)((u + 0x7FFFu + ((u >> 16) & 1u)) >> 16);
}
__device__ __forceinline__ float bf2f(ushort_t h) {
  return __uint_as_float(((unsigned)h) << 16);
}

// blk 0: zero scalars; blk 1..12: concat [bq;bk;bv] -> BQKV
__global__ void init_kernel(float* __restrict__ s,
                            const float* __restrict__ bq, const float* __restrict__ bk,
                            const float* __restrict__ bv, float* __restrict__ o) {
  if (blockIdx.x == 0) { s[threadIdx.x] = 0.0f; return; }
  int t = (blockIdx.x - 1) * 256 + threadIdx.x;   // 0..3071
  o[t] = (t < 1024) ? bq[t] : (t < 2048) ? bk[t - 1024] : bv[t - 2048];
}

// ---------------------------------------------------------------------------
// merged absmax of 6 weights (segmented grid-stride)
// ---------------------------------------------------------------------------
__global__ __launch_bounds__(256) void absmax6_kernel(
    const float* __restrict__ Wq, const float* __restrict__ Wk,
    const float* __restrict__ Wv, const float* __restrict__ Wo,
    const float* __restrict__ W1, const float* __restrict__ W2,
    float* __restrict__ Sc)
{
  const u64 DD = (u64)Ddim * Ddim;
  int blk = blockIdx.x;
  const float* src; float* dst; u64 lb, nb, n;
  if (blk < 256)       { src = Wq; dst = Sc + 1; lb = blk;        nb = 256;  n = DD; }
  else if (blk < 512)  { src = Wk; dst = Sc + 2; lb = blk - 256;  nb = 256;  n = DD; }
  else if (blk < 768)  { src = Wv; dst = Sc + 3; lb = blk - 512;  nb = 256;  n = DD; }
  else if (blk < 1024) { src = Wo; dst = Sc + 4; lb = blk - 768;  nb = 256;  n = DD; }
  else if (blk < 2048) { src = W1; dst = Sc + 5; lb = blk - 1024; nb = 1024; n = 4 * DD; }
  else                 { src = W2; dst = Sc + 6; lb = blk - 2048; nb = 1024; n = 4 * DD; }
  u64 i = lb * 256 + threadIdx.x;
  u64 stride = nb * 256;
  float m = 0.0f;
  for (; i < n; i += stride) m = fmaxf(m, fabsf(src[i]));
  m = blockMax256(m);
  if (threadIdx.x == 0) atomicMaxF(dst, m);
}

// ---------------------------------------------------------------------------
// merged weight quantization: Wq/Wk/Wv/W1/W2 -> int8, Wo -> int-in-bf16
// ---------------------------------------------------------------------------
__global__ __launch_bounds__(256) void quantw_kernel(
    const float* __restrict__ Wq, const float* __restrict__ Wk,
    const float* __restrict__ Wv, const float* __restrict__ Wo,
    const float* __restrict__ W1, const float* __restrict__ W2,
    signed char* __restrict__ Wq8, signed char* __restrict__ Wk8,
    signed char* __restrict__ Wv8, ushort_t* __restrict__ WoBF,
    signed char* __restrict__ W18, signed char* __restrict__ W28,
    const float* __restrict__ Sc)
{
  const u64 DD = (u64)Ddim * Ddim;
  int blk = blockIdx.x;
  if (blk < 2816) {   // int8 path (float4 units)
    const float* src; signed char* dst; float sa; u64 lb, nb, n4;
    if (blk < 256)       { src = Wq; dst = Wq8; sa = Sc[1]; lb = blk;        nb = 256;  n4 = DD / 4; }
    else if (blk < 512)  { src = Wk; dst = Wk8; sa = Sc[2]; lb = blk - 256;  nb = 256;  n4 = DD / 4; }
    else if (blk < 768)  { src = Wv; dst = Wv8; sa = Sc[3]; lb = blk - 512;  nb = 256;  n4 = DD / 4; }
    else if (blk < 1792) { src = W1; dst = W18; sa = Sc[5]; lb = blk - 768;  nb = 1024; n4 = DD; }
    else                 { src = W2; dst = W28; sa = Sc[6]; lb = blk - 1792; nb = 1024; n4 = DD; }
    const float is = 1.0f / fmaxf(sa / 127.0f, 1e-8f);
    u64 i = lb * 256 + threadIdx.x;
    u64 stride = nb * 256;
    for (; i < n4; i += stride) {
      float4 v = ((const float4*)src)[i];
      int b0 = (int)fminf(fmaxf(rintf(v.x * is), -128.0f), 127.0f) & 255;
      int b1 = (int)fminf(fmaxf(rintf(v.y * is), -128.0f), 127.0f) & 255;
      int b2 = (int)fminf(fmaxf(rintf(v.z * is), -128.0f), 127.0f) & 255;
      int b3 = (int)fminf(fmaxf(rintf(v.w * is), -128.0f), 127.0f) & 255;
      ((unsigned*)dst)[i] = (unsigned)(b0 | (b1 << 8) | (b2 << 16) | (b3 << 24));
    }
  } else {            // Wo -> exact int in bf16
    const float is = 1.0f / fmaxf(Sc[4] / 127.0f, 1e-8f);
    u64 i = (u64)(blk - 2816) * 256 + threadIdx.x;
    u64 stride = 1024ull * 256;
    for (; i < DD; i += stride) {
      float r = fminf(fmaxf(rintf(Wo[i] * is), -128.0f), 127.0f);
      WoBF[i] = f2bf(r);
    }
  }
}

// ---------------------------------------------------------------------------
// quantize fp32 -> int8 (packed 4/thread) — activations feeding GEMMs
// ---------------------------------------------------------------------------
__global__ __launch_bounds__(256) void quant8_kernel(
    const float* __restrict__ x, const float* __restrict__ amaxp,
    signed char* __restrict__ q, u64 n4)
{
  const float is = 1.0f / fmaxf(*amaxp / 127.0f, 1e-8f);
  u64 i = (u64)blockIdx.x * 256 + threadIdx.x;
  u64 stride = (u64)gridDim.x * 256;
  for (; i < n4; i += stride) {
    float4 v = ((const float4*)x)[i];
    int b0 = (int)fminf(fmaxf(rintf(v.x * is), -128.0f), 127.0f) & 255;
    int b1 = (int)fminf(fmaxf(rintf(v.y * is), -128.0f), 127.0f) & 255;
    int b2 = (int)fminf(fmaxf(rintf(v.z * is), -128.0f), 127.0f) & 255;
    int b3 = (int)fminf(fmaxf(rintf(v.w * is), -128.0f), 127.0f) & 255;
    ((unsigned*)q)[i] = (unsigned)(b0 | (b1 << 8) | (b2 << 16) | (b3 << 24));
  }
}

// ---------------------------------------------------------------------------
// LayerNorm (one block per row of 1024), optional input qdq, output absmax
// ---------------------------------------------------------------------------
__global__ __launch_bounds__(256) void ln_kernel(
    const float* __restrict__ x, const float* __restrict__ g,
    const float* __restrict__ beta, const float* __restrict__ inAmax,
    float* __restrict__ y, float* __restrict__ amaxOut)
{
  __shared__ float sred[4];
  __shared__ float smv[2];
  const int tid = threadIdx.x;
  const u64 row = blockIdx.x;
  const float* xr = x + row * Ddim;
  float* yr = y + row * Ddim;
  float aIn = inAmax ? *inAmax : 0.0f;

  float vals[4];
  float sum = 0.0f;
  #pragma unroll
  for (int i = 0; i < 4; i++) {
    float v = xr[tid + (i << 8)];
    if (inAmax) v = qdq_f(v, aIn);
    vals[i] = v;
    sum += v;
  }
  #pragma unroll
  for (int o = 32; o > 0; o >>= 1) sum += __shfl_xor(sum, o);
  if ((tid & 63) == 0) sred[tid >> 6] = sum;
  __syncthreads();
  if (tid == 0) smv[0] = (sred[0] + sred[1] + sred[2] + sred[3]) * (1.0f / 1024.0f);
  __syncthreads();
  const float mean = smv[0];

  float dev = 0.0f;
  #pragma unroll
  for (int i = 0; i < 4; i++) { float d = vals[i] - mean; dev += d * d; }
  #pragma unroll
  for (int o = 32; o > 0; o >>= 1) dev += __shfl_xor(dev, o);
  if ((tid & 63) == 0) sred[tid >> 6] = dev;
  __syncthreads();
  if (tid == 0) {
    float var = (sred[0] + sred[1] + sred[2] + sred[3]) * (1.0f / 1024.0f);
    smv[1] = 1.0f / sqrtf(var + 1e-5f);
  }
  __syncthreads();
  const float inv = smv[1];

  float lmax = 0.0f;
  #pragma unroll
  for (int i = 0; i < 4; i++) {
    int c = tid + (i << 8);
    float ov = (vals[i] - mean) * inv * g[c] + beta[c];
    yr[c] = ov;
    lmax = fmaxf(lmax, fabsf(ov));
  }
  #pragma unroll
  for (int o = 32; o > 0; o >>= 1) lmax = fmaxf(lmax, __shfl_xor(lmax, o));
  __syncthreads();
  if ((tid & 63) == 0) sred[tid >> 6] = lmax;
  __syncthreads();
  if (tid == 0)
    atomicMaxF(amaxOut, fmaxf(fmaxf(sred[0], sred[1]), fmaxf(sred[2], sred[3])));
}

// ---------------------------------------------------------------------------
// i8 MFMA GEMM: C[M,N] = (A8[M,K] @ B8[N,K]^T)*sA*sB + bias[N]
// 128x128 tile, BK=64, 2x2 waves x 4x4 mfma_i32_16x16x64_i8 tiles.
// EPI: 0 none; 1 gelu+amax; 2 +qdq(T)+amax (fused residual add)
// ---------------------------------------------------------------------------
template <int EPI>
__global__ __launch_bounds__(256) void gemm_i8(
    const signed char* __restrict__ A8, const signed char* __restrict__ B8,
    const float* __restrict__ bias, float* __restrict__ C,
    int M, int N, int K,
    const float* __restrict__ sAp, const float* __restrict__ sBp,
    float* __restrict__ amaxOut,
    const float* __restrict__ Tm = nullptr,
    const float* __restrict__ amaxT = nullptr)
{
  __shared__ __align__(16) signed char As[128][80];
  __shared__ __align__(16) signed char Bs[128][80];
  const int tid = threadIdx.x;
  const int wave = tid >> 6, lane = tid & 63;
  const int quad = lane >> 4, l16 = lane & 15;
  const int wy = wave >> 1, wx = wave & 1;
  const int m0 = blockIdx.y << 7, n0 = blockIdx.x << 7;
  const float sA = fmaxf(*sAp / 127.0f, 1e-8f);
  const float sB = fmaxf(*sBp / 127.0f, 1e-8f);
  const float sAB = sA * sB;
  const float aT = (EPI == 2) ? *amaxT : 0.0f;

  const int sr = tid >> 2;            // staging row 0..63
  const int sc = (tid & 3) << 4;      // staging byte col 0/16/32/48

  int4v acc[4][4] = {};
  for (int k0 = 0; k0 < K; k0 += 64) {
    #pragma unroll
    for (int p = 0; p < 2; p++) {
      int r = sr + (p << 6);
      uint4 av = *(const uint4*)&A8[(u64)(m0 + r) * K + k0 + sc];
      uint4 bv = *(const uint4*)&B8[(u64)(n0 + r) * K + k0 + sc];
      *(uint4*)&As[r][sc] = av;
      *(uint4*)&Bs[r][sc] = bv;
    }
    __syncthreads();
    int4v af[4], bf[4];
    #pragma unroll
    for (int mt = 0; mt < 4; mt++)
      af[mt] = *(const int4v*)&As[(wy << 6) + (mt << 4) + l16][quad << 4];
    #pragma unroll
    for (int nt = 0; nt < 4; nt++)
      bf[nt] = *(const int4v*)&Bs[(wx << 6) + (nt << 4) + l16][quad << 4];
    #pragma unroll
    for (int mt = 0; mt < 4; mt++)
      #pragma unroll
      for (int nt = 0; nt < 4; nt++)
        acc[mt][nt] = __builtin_amdgcn_mfma_i32_16x16x64_i8(af[mt], bf[nt], acc[mt][nt], 0, 0, 0);
    __syncthreads();
  }

  float lmax = 0.0f;
  #pragma unroll
  for (int mt = 0; mt < 4; mt++) {
    #pragma unroll
    for (int reg = 0; reg < 4; reg++) {
      int row = m0 + (wy << 6) + (mt << 4) + (quad << 2) + reg;
      #pragma unroll
      for (int nt = 0; nt < 4; nt++) {
        int col = n0 + (wx << 6) + (nt << 4) + l16;
        float v = (float)acc[mt][nt][reg] * sAB + bias[col];
        if (EPI == 1) {
          v = 0.5f * v * (1.0f + erff(v * 0.70710678118654752440f));
          lmax = fmaxf(lmax, fabsf(v));
        }
        if (EPI == 2) {
          v += qdq_f(Tm[(u64)row * N + col], aT);
          lmax = fmaxf(lmax, fabsf(v));
        }
        C[(u64)row * N + col] = v;
      }
    }
  }
  if (EPI >= 1) {
    lmax = blockMax256(lmax);
    if (tid == 0) atomicMaxF(amaxOut, lmax);
  }
}

// ---------------------------------------------------------------------------
// plain mega-QKV i8 GEMM: C[M,3072] = A8 @ [Wq8;Wk8;Wv8]^T + BQKV
// per-segment weight scale (seg = n0>>10). Epilogue = store only (no
// transcendentals -> no libcall spills; see R7 post-mortem).
// ---------------------------------------------------------------------------
__global__ __launch_bounds__(256) void gemm_qkv3(
    const signed char* __restrict__ A8, const signed char* __restrict__ B8,
    const float* __restrict__ bias, float* __restrict__ C,
    const float* __restrict__ Sc)
{
  __shared__ __align__(16) signed char As[128][80];
  __shared__ __align__(16) signed char Bs[128][80];
  const int tid = threadIdx.x;
  const int wave = tid >> 6, lane = tid & 63;
  const int quad = lane >> 4, l16 = lane & 15;
  const int wy = wave >> 1, wx = wave & 1;
  const int m0 = blockIdx.y << 7, n0 = blockIdx.x << 7;
  const int K = Ddim, N = 3 * Ddim;
  const int seg = n0 >> 10;
  const float sA = fmaxf(Sc[0] / 127.0f, 1e-8f);
  const float sB = fmaxf(Sc[1 + seg] / 127.0f, 1e-8f);
  const float sAB = sA * sB;

  const int sr = tid >> 2;
  const int sc_ = (tid & 3) << 4;

  int4v acc[4][4] = {};
  for (int k0 = 0; k0 < K; k0 += 64) {
    #pragma unroll
    for (int p = 0; p < 2; p++) {
      int r = sr + (p << 6);
      uint4 av = *(const uint4*)&A8[(u64)(m0 + r) * K + k0 + sc_];
      uint4 bv = *(const uint4*)&B8[(u64)(n0 + r) * K + k0 + sc_];
      *(uint4*)&As[r][sc_] = av;
      *(uint4*)&Bs[r][sc_] = bv;
    }
    __syncthreads();
    int4v af[4], bf[4];
    #pragma unroll
    for (int mt = 0; mt < 4; mt++)
      af[mt] = *(const int4v*)&As[(wy << 6) + (mt << 4) + l16][quad << 4];
    #pragma unroll
    for (int nt = 0; nt < 4; nt++)
      bf[nt] = *(const int4v*)&Bs[(wx << 6) + (nt << 4) + l16][quad << 4];
    #pragma unroll
    for (int mt = 0; mt < 4; mt++)
      #pragma unroll
      for (int nt = 0; nt < 4; nt++)
        acc[mt][nt] = __builtin_amdgcn_mfma_i32_16x16x64_i8(af[mt], bf[nt], acc[mt][nt], 0, 0, 0);
    __syncthreads();
  }

  #pragma unroll
  for (int mt = 0; mt < 4; mt++) {
    #pragma unroll
    for (int reg = 0; reg < 4; reg++) {
      int row = m0 + (wy << 6) + (mt << 4) + (quad << 2) + reg;
      #pragma unroll
      for (int nt = 0; nt < 4; nt++) {
        int col = n0 + (wx << 6) + (nt << 4) + l16;
        C[(u64)row * N + col] = (float)acc[mt][nt][reg] * sAB + bias[col];
      }
    }
  }
}

// ---------------------------------------------------------------------------
// bf16-split MFMA GEMM for Wo: C = ((Ahi+Alo)[M,K] @ Wq[N,K]^T)*sW + bias
// ---------------------------------------------------------------------------
__global__ __launch_bounds__(256) void gemm_bf16_wo(
    const ushort_t* __restrict__ Ahi, const ushort_t* __restrict__ Alo,
    const ushort_t* __restrict__ Bw, const float* __restrict__ bias,
    float* __restrict__ C, int M, int N, int K,
    const float* __restrict__ sWp, float* __restrict__ amaxOut)
{
  __shared__ __align__(16) ushort_t Hs[128][40];
  __shared__ __align__(16) ushort_t Ls[128][40];
  __shared__ __align__(16) ushort_t Ws[128][40];
  const int tid = threadIdx.x;
  const int wave = tid >> 6, lane = tid & 63;
  const int quad = lane >> 4, l16 = lane & 15;
  const int wy = wave >> 1, wx = wave & 1;
  const int m0 = blockIdx.y << 7, n0 = blockIdx.x << 7;
  const float sW = fmaxf(*sWp / 127.0f, 1e-8f);

  const int sr = tid >> 2;
  const int sce = (tid & 3) << 3;

  float4v acc[4][4] = {};
  for (int k0 = 0; k0 < K; k0 += 32) {
    #pragma unroll
    for (int p = 0; p < 2; p++) {
      int r = sr + (p << 6);
      uint4 hv = *(const uint4*)&Ahi[(u64)(m0 + r) * K + k0 + sce];
      uint4 lv = *(const uint4*)&Alo[(u64)(m0 + r) * K + k0 + sce];
      uint4 wv = *(const uint4*)&Bw[(u64)(n0 + r) * K + k0 + sce];
      *(uint4*)&Hs[r][sce] = hv;
      *(uint4*)&Ls[r][sce] = lv;
      *(uint4*)&Ws[r][sce] = wv;
    }
    __syncthreads();
    short8v ah[4], al[4], bw[4];
    #pragma unroll
    for (int mt = 0; mt < 4; mt++) {
      ah[mt] = *(const short8v*)&Hs[(wy << 6) + (mt << 4) + l16][quad << 3];
      al[mt] = *(const short8v*)&Ls[(wy << 6) + (mt << 4) + l16][quad << 3];
    }
    #pragma unroll
    for (int nt = 0; nt < 4; nt++)
      bw[nt] = *(const short8v*)&Ws[(wx << 6) + (nt << 4) + l16][quad << 3];
    #pragma unroll
    for (int mt = 0; mt < 4; mt++)
      #pragma unroll
      for (int nt = 0; nt < 4; nt++) {
        acc[mt][nt] = __builtin_amdgcn_mfma_f32_16x16x32_bf16(ah[mt], bw[nt], acc[mt][nt], 0, 0, 0);
        acc[mt][nt] = __builtin_amdgcn_mfma_f32_16x16x32_bf16(al[mt], bw[nt], acc[mt][nt], 0, 0, 0);
      }
    __syncthreads();
  }

  float lmax = 0.0f;
  #pragma unroll
  for (int mt = 0; mt < 4; mt++) {
    #pragma unroll
    for (int reg = 0; reg < 4; reg++) {
      int row = m0 + (wy << 6) + (mt << 4) + (quad << 2) + reg;
      #pragma unroll
      for (int nt = 0; nt < 4; nt++) {
        int col = n0 + (wx << 6) + (nt << 4) + l16;
        float v = acc[mt][nt][reg] * sW + bias[col];
        lmax = fmaxf(lmax, fabsf(v));
        C[(u64)row * N + col] = v;
      }
    }
  }
  lmax = blockMax256(lmax);
  if (tid == 0) atomicMaxF(amaxOut, lmax);
}

// ---------------------------------------------------------------------------
// prep_attn: rope(q)*0.125, rope(k), hi/lo bf16 split, V transpose, norms.
// In:  QKV fp32 [row][3072] (cols 0..1023 q, 1024..2047 k, 2048..3071 v)
// Out: QH/QL/KH/KL ushort [bh][s][hd];  VTH/VTL ushort [bh][hd][s]
// grid (S/64, B*H), block 256. (memory-bound; libcalls harmless here — R7)
// ---------------------------------------------------------------------------
__global__ __launch_bounds__(256) void prep_attn(
    const float* __restrict__ QKV,
    ushort_t* __restrict__ QH, ushort_t* __restrict__ QL,
    ushort_t* __restrict__ KH, ushort_t* __restrict__ KL,
    ushort_t* __restrict__ VTH, ushort_t* __restrict__ VTL,
    float* __restrict__ NQ, float* __restrict__ KMX)
{
  const int bh = blockIdx.y;
  const int b = bh >> 4, h = bh & 15;
  const int s0 = blockIdx.x << 6;
  const int tid = threadIdx.x;
  float kml = 0.0f;

  // --- q/k rope + scale + split + norms (2048 pairs) ---
  #pragma unroll
  for (int i = 0; i < 8; i++) {
    int idx = tid + (i << 8);          // 0..2047
    int s = idx >> 5, hp = idx & 31;
    int sa = s0 + s;
    u64 gin = (u64)(b * Sdim + sa) * 3072 + (h << 6) + hp;
    float inv = powf(10000.0f, -(float)hp * (1.0f / 32.0f));
    float ang = (float)sa * inv;
    float cs = cosf(ang), sn = sinf(ang);
    float q1 = QKV[gin],        q2 = QKV[gin + 32];
    float k1 = QKV[gin + 1024], k2 = QKV[gin + 1056];
    float qo1 = (q1 * cs - q2 * sn) * 0.125f;
    float qo2 = (q1 * sn + q2 * cs) * 0.125f;
    float ko1 = k1 * cs - k2 * sn;
    float ko2 = k1 * sn + k2 * cs;
    u64 go = ((u64)bh * Sdim + sa) * HDdim + hp;
    ushort_t t;
    t = f2bf(qo1); QH[go]      = t; QL[go]      = f2bf(qo1 - bf2f(t));
    t = f2bf(qo2); QH[go + 32] = t; QL[go + 32] = f2bf(qo2 - bf2f(t));
    t = f2bf(ko1); KH[go]      = t; KL[go]      = f2bf(ko1 - bf2f(t));
    t = f2bf(ko2); KH[go + 32] = t; KL[go + 32] = f2bf(ko2 - bf2f(t));
    float nq2 = qo1 * qo1 + qo2 * qo2;
    float nk2 = ko1 * ko1 + ko2 * ko2;
    #pragma unroll
    for (int o = 16; o >= 1; o >>= 1) {
      nq2 += __shfl_xor(nq2, o);
      nk2 += __shfl_xor(nk2, o);
    }
    if (hp == 0) {
      NQ[(u64)bh * Sdim + sa] = sqrtf(nq2);
      kml = fmaxf(kml, sqrtf(nk2));
    }
  }
  kml = blockMax256(kml);
  if (tid == 0) atomicMaxF(&KMX[bh], kml);

  // --- v: split + transpose via LDS ---
  __shared__ ushort_t VHs[64][66], VLs[64][66];
  #pragma unroll
  for (int i = 0; i < 4; i++) {
    int idx4 = tid + (i << 8);         // 0..1023
    int s = idx4 >> 4, c4 = (idx4 & 15) << 2;
    u64 gin = (u64)(b * Sdim + s0 + s) * 3072 + 2048 + (h << 6) + c4;
    float4 vv = *(const float4*)&QKV[gin];
    float va[4] = {vv.x, vv.y, vv.z, vv.w};
    #pragma unroll
    for (int j = 0; j < 4; j++) {
      ushort_t vh = f2bf(va[j]);
      VHs[s][c4 + j] = vh;
      VLs[s][c4 + j] = f2bf(va[j] - bf2f(vh));
    }
  }
  __syncthreads();
  #pragma unroll
  for (int i = 0; i < 4; i++) {
    int idx4 = tid + (i << 8);
    int hd = idx4 >> 4, s4 = (idx4 & 15) << 2;
    us4v oh, ol;
    #pragma unroll
    for (int j = 0; j < 4; j++) { oh[j] = VHs[s4 + j][hd]; ol[j] = VLs[s4 + j][hd]; }
    u64 go = ((u64)bh * HDdim + hd) * Sdim + s0 + s4;
    *(us4v*)&VTH[go] = oh;
    *(us4v*)&VTL[go] = ol;
  }
}

// ---------------------------------------------------------------------------
// MFMA flash attention v5: KV tile 32, 128 q-rows/block, 4 waves x 32 (mt=2).
// LDS = K(9216) + V^T(10240) + PF(18432) = 37888 B -> 4 blocks/CU (16
// waves/CU) for 2x the chain-level overlap of v3. Same MFMA sequence as
// v3 (bit-identical oacc); only lsum grouping differs (ulp-class).
// No transcendental libcalls (R7); mt=2 register budget (R9); no XCD
// swizzle (R10: attn is not HBM-bound, swizzle was -5%).
// ---------------------------------------------------------------------------
__global__ __launch_bounds__(256) void attn_kernel(
    const ushort_t* __restrict__ QH, const ushort_t* __restrict__ QL,
    const ushort_t* __restrict__ KH, const ushort_t* __restrict__ KL,
    const ushort_t* __restrict__ VTH, const ushort_t* __restrict__ VTL,
    const float* __restrict__ NQ, const float* __restrict__ KMX,
    ushort_t* __restrict__ OHI, ushort_t* __restrict__ OLO)
{
  __shared__ __align__(16) ushort_t KHs[32][72], KLs[32][72];
  __shared__ __align__(16) ushort_t VHs[64][40], VLs[64][40];   // V^T [hd][kv]
  __shared__ __align__(16) float PF[128][36];
  const int tid = threadIdx.x;
  const int wave = tid >> 6, lane = tid & 63;
  const int quad = lane >> 4, l16 = lane & 15;
  const int w32 = wave << 5;
  const int bh = blockIdx.y;
  const int b = bh >> 4, h = bh & 15;
  const int q0 = blockIdx.x << 7;
  const u64 bhS = (u64)bh * Sdim;

  // ---- Q fragments -> registers (A-layout: m=l16, k=quad*8+j) ----
  short8v qh[2][2], ql[2][2];
  #pragma unroll
  for (int mt = 0; mt < 2; mt++)
    #pragma unroll
    for (int kk = 0; kk < 2; kk++) {
      u64 g = (bhS + q0 + w32 + (mt << 4) + l16) * HDdim + (kk << 5) + (quad << 3);
      qh[mt][kk] = *(const short8v*)&QH[g];
      ql[mt][kk] = *(const short8v*)&QL[g];
    }

  const float kmax = KMX[bh] * 1.0009765625f;
  float Mb[2][4], lsum[2][4];
  #pragma unroll
  for (int mt = 0; mt < 2; mt++)
    #pragma unroll
    for (int r = 0; r < 4; r++) {
      Mb[mt][r] = NQ[bhS + q0 + w32 + (mt << 4) + (quad << 2) + r] * kmax;
      lsum[mt][r] = 0.0f;
    }

  float4v oacc[2][4] = {};

  for (int j0 = 0; j0 < Sdim; j0 += 32) {
    __syncthreads();
    {
      int r = tid >> 3, c8 = (tid & 7) << 3;       // K: 32 rows x 64 hd
      u64 gk = (bhS + j0 + r) * HDdim + c8;
      *(uint4*)&KHs[r][c8] = *(const uint4*)&KH[gk];
      *(uint4*)&KLs[r][c8] = *(const uint4*)&KL[gk];
      int r2 = tid >> 2, c82 = (tid & 3) << 3;     // V^T: 64 hd x 32 kv
      u64 gv = ((u64)bh * HDdim + r2) * Sdim + j0 + c82;
      *(uint4*)&VHs[r2][c82] = *(const uint4*)&VTH[gv];
      *(uint4*)&VLs[r2][c82] = *(const uint4*)&VTL[gv];
    }
    __syncthreads();

    // ---- scores = Q K^T (3-term hi/lo); nt spans 2 kv 16-tiles ----
    float4v sc[2][2] = {};
    #pragma unroll
    for (int kk = 0; kk < 2; kk++) {
      short8v kf_h[2], kf_l[2];
      #pragma unroll
      for (int nt = 0; nt < 2; nt++) {
        kf_h[nt] = *(const short8v*)&KHs[(nt << 4) + l16][(kk << 5) + (quad << 3)];
        kf_l[nt] = *(const short8v*)&KLs[(nt << 4) + l16][(kk << 5) + (quad << 3)];
      }
      #pragma unroll
      for (int mt = 0; mt < 2; mt++)
        #pragma unroll
        for (int nt = 0; nt < 2; nt++) {
          sc[mt][nt] = __builtin_amdgcn_mfma_f32_16x16x32_bf16(qh[mt][kk], kf_h[nt], sc[mt][nt], 0, 0, 0);
          sc[mt][nt] = __builtin_amdgcn_mfma_f32_16x16x32_bf16(qh[mt][kk], kf_l[nt], sc[mt][nt], 0, 0, 0);
          sc[mt][nt] = __builtin_amdgcn_mfma_f32_16x16x32_bf16(ql[mt][kk], kf_h[nt], sc[mt][nt], 0, 0, 0);
        }
    }

    // ---- static-max softmax: p = exp(s - M), partial l; P -> per-wave LDS
    #pragma unroll
    for (int mt = 0; mt < 2; mt++)
      #pragma unroll
      for (int r = 0; r < 4; r++) {
        int prow = w32 + (mt << 4) + (quad << 2) + r;
        float p0 = __expf(sc[mt][0][r] - Mb[mt][r]);
        float p1 = __expf(sc[mt][1][r] - Mb[mt][r]);
        PF[prow][l16] = p0;
        PF[prow][16 + l16] = p1;
        lsum[mt][r] += p0 + p1;
      }
    // no barrier: each wave reads only its own P rows (RAW via lgkmcnt)

    // ---- O += P V (V-frags hoisted over mt; single kk since KV=32) ----
    short8v vh[4], vl[4];
    #pragma unroll
    for (int nt = 0; nt < 4; nt++) {
      vh[nt] = *(const short8v*)&VHs[(nt << 4) + l16][quad << 3];
      vl[nt] = *(const short8v*)&VLs[(nt << 4) + l16][quad << 3];
    }
    #pragma unroll
    for (int mt = 0; mt < 2; mt++) {
      const float* prp = &PF[w32 + (mt << 4) + l16][quad << 3];
      float4v pa = *(const float4v*)prp;
      float4v pb = *(const float4v*)(prp + 4);
      short8v ph, pl;
      #pragma unroll
      for (int j = 0; j < 4; j++) {
        unsigned ua = __float_as_uint(pa[j]);
        unsigned ub = __float_as_uint(pb[j]);
        float la = pa[j] - __uint_as_float(ua & 0xffff0000u);
        float lb = pb[j] - __uint_as_float(ub & 0xffff0000u);
        ph[j]     = (short)(ua >> 16);
        ph[4 + j] = (short)(ub >> 16);
        pl[j]     = (short)(__float_as_uint(la) >> 16);
        pl[4 + j] = (short)(__float_as_uint(lb) >> 16);
      }
      #pragma unroll
      for (int nt = 0; nt < 4; nt++) {
        oacc[mt][nt] = __builtin_amdgcn_mfma_f32_16x16x32_bf16(ph, vh[nt], oacc[mt][nt], 0, 0, 0);
        oacc[mt][nt] = __builtin_amdgcn_mfma_f32_16x16x32_bf16(ph, vl[nt], oacc[mt][nt], 0, 0, 0);
        oacc[mt][nt] = __builtin_amdgcn_mfma_f32_16x16x32_bf16(pl, vh[nt], oacc[mt][nt], 0, 0, 0);
      }
    }
  }

  // ---- one l-reduction over the 16 l16 lanes ----
  #pragma unroll
  for (int mt = 0; mt < 2; mt++)
    #pragma unroll
    for (int r = 0; r < 4; r++) {
      float l = lsum[mt][r];
      #pragma unroll
      for (int o = 8; o >= 1; o >>= 1) l += __shfl_xor(l, o);
      lsum[mt][r] = l;
    }

  // ---- epilogue: o = O/l, split hi/lo, write [b][s][h][hd] ----
  #pragma unroll
  for (int mt = 0; mt < 2; mt++)
    #pragma unroll
    for (int r = 0; r < 4; r++) {
      float invl = 1.0f / lsum[mt][r];
      int srow = q0 + w32 + (mt << 4) + (quad << 2) + r;
      u64 gbase = ((u64)(b * Sdim + srow) * Hdim + h) * HDdim;
      #pragma unroll
      for (int nt = 0; nt < 4; nt++) {
        float o = oacc[mt][nt][r] * invl;
        ushort_t t = f2bf(o);
        OHI[gbase + (nt << 4) + l16] = t;
        OLO[gbase + (nt << 4) + l16] = f2bf(o - bf2f(t));
      }
    }
}

// ---------------------------------------------------------------------------
// elementwise stages
// ---------------------------------------------------------------------------
__global__ __launch_bounds__(256) void add_qdq_kernel(
    const float* __restrict__ a, const float* __restrict__ amaxA,
    const float* __restrict__ x, float* __restrict__ outp, u64 n,
    float* __restrict__ amaxOut)
{
  const float aA = *amaxA;
  u64 i = (u64)blockIdx.x * 256 + threadIdx.x;
  u64 stride = (u64)gridDim.x * 256;
  float m = 0.0f;
  for (; i < n; i += stride) {
    float t = qdq_f(a[i], aA) + x[i];
    outp[i] = t;
    m = fmaxf(m, fabsf(t));
  }
  m = blockMax256(m);
  if (threadIdx.x == 0) atomicMaxF(amaxOut, m);
}

__global__ __launch_bounds__(256) void qdq_out_kernel(
    const float* __restrict__ u, const float* __restrict__ amaxU,
    float* __restrict__ o, u64 n)
{
  const float aU = *amaxU;
  u64 i = (u64)blockIdx.x * 256 + threadIdx.x;
  u64 stride = (u64)gridDim.x * 256;
  for (; i < n; i += stride) o[i] = qdq_f(u[i], aU);
}

// ---------------------------------------------------------------------------
// launch
// ---------------------------------------------------------------------------
extern "C" void kernel_launch(void* const* d_in, const int* in_sizes, int n_in,
                              void* d_out, int out_size, void* d_ws, size_t ws_size,
                              hipStream_t stream)
{
  const float* x   = (const float*)d_in[0];
  const float* g1  = (const float*)d_in[1];
  const float* bn1 = (const float*)d_in[2];
  const float* Wq  = (const float*)d_in[3];
  const float* bq  = (const float*)d_in[4];
  const float* Wk  = (const float*)d_in[5];
  const float* bk  = (const float*)d_in[6];
  const float* Wv  = (const float*)d_in[7];
  const float* bv  = (const float*)d_in[8];
  const float* Wo  = (const float*)d_in[9];
  const float* bo  = (const float*)d_in[10];
  const float* g2  = (const float*)d_in[11];
  const float* bn2 = (const float*)d_in[12];
  const float* W1  = (const float*)d_in[13];
  const float* bf1 = (const float*)d_in[14];
  const float* W2  = (const float*)d_in[15];
  const float* bf2 = (const float*)d_in[16];
  float* out = (float*)d_out;

  const u64 NBSD = (u64)Bdim * Sdim * Ddim;     // 8,388,608
  const u64 NB4  = NBSD * 4;
  const u64 DD   = (u64)Ddim * Ddim;

  char* Wb = (char*)d_ws;
  float*       Sc   = (float*)Wb;                // 0-11 scales, 128.. KMX[64]
  float*       U0   = (float*)(Wb + 1024);
  float*       U1   = (float*)(Wb + 1024 + NB4);
  float*       F    = (float*)(Wb + 1024 + 2 * NB4);
  signed char* A8   = (signed char*)(Wb + 1024 + 6 * NB4);
  signed char* Wq8  = A8 + NBSD;                 // [Wq8;Wk8;Wv8] contiguous
  signed char* Wk8  = Wq8 + DD;
  signed char* Wv8  = Wk8 + DD;
  signed char* W18  = Wv8 + DD;
  signed char* W28  = W18 + 4 * DD;
  ushort_t*    WoBF = (ushort_t*)(W28 + 4 * DD);
  float*       NQ   = (float*)(WoBF + DD);       // 64*2048 floats
  float*       BQKV = NQ + (u64)64 * Sdim;       // 3072 floats
  float*       KMX  = Sc + 128;

  // overlays (lifetime-checked):
  float* QKV = U1;                                // fp32 [8192][3072] = U1,F0,F1
  float* F0  = F;                                 // o fp32 (post-Wo)
  ushort_t* QHp = (ushort_t*)(F + 2 * NBSD);      // Q hi/lo
  ushort_t* QLp = QHp + NBSD;
  ushort_t* KHp = (ushort_t*)(F + 3 * NBSD);      // K hi/lo
  ushort_t* KLp = KHp + NBSD;
  ushort_t* VTH = (ushort_t*)U0;                  // V^T hi/lo
  ushort_t* VTL = VTH + NBSD;
  ushort_t* OHI = (ushort_t*)U1;                  // attn out hi/lo (QKV dead)
  ushort_t* OLO = OHI + NBSD;
  signed char* G8 = (signed char*)U0;             // gelu int8 (VT dead by then)

  const u64 needBytes = (u64)((char*)(BQKV + 3072) - Wb);
  if (ws_size < needBytes) return;

  // scales: 0:h1 1:Wq 2:Wk 3:Wv 4:Wo 5:W1 6:W2 7:o_proj 8:t 9:h2 10:gelu 11:final
  init_kernel<<<13, 256, 0, stream>>>(Sc, bq, bk, bv, BQKV);

  ln_kernel<<<Bdim * Sdim, 256, 0, stream>>>(x, g1, bn1, nullptr, U0, Sc + 0);

  absmax6_kernel<<<3072, 256, 0, stream>>>(Wq, Wk, Wv, Wo, W1, W2, Sc);

  quant8_kernel<<<4096, 256, 0, stream>>>(U0, Sc + 0, A8, NBSD / 4);
  quantw_kernel<<<3840, 256, 0, stream>>>(Wq, Wk, Wv, Wo, W1, W2,
                                          Wq8, Wk8, Wv8, WoBF, W18, W28, Sc);

  const int M = Bdim * Sdim;                     // 8192

  // single plain QKV gemm -> fp32 [row][3072]
  dim3 gQKV(3 * Ddim / 128, M / 128);            // (24, 64)
  gemm_qkv3<<<gQKV, 256, 0, stream>>>(A8, Wq8, BQKV, QKV, Sc);

  dim3 gPrep(Sdim / 64, Bdim * Hdim);            // (32, 64)
  prep_attn<<<gPrep, 256, 0, stream>>>(QKV, QHp, QLp, KHp, KLp, VTH, VTL, NQ, KMX);

  dim3 gAttn(Sdim / 128, Bdim * Hdim);           // (16, 64)
  attn_kernel<<<gAttn, 256, 0, stream>>>(QHp, QLp, KHp, KLp, VTH, VTL, NQ, KMX, OHI, OLO);

  dim3 gP(Ddim / 128, M / 128);                  // (8, 64)
  gemm_bf16_wo<<<gP, 256, 0, stream>>>(OHI, OLO, WoBF, bo, F0, M, Ddim, Ddim, Sc + 4, Sc + 7);

  // t = fq(o) + x -> U1
  add_qdq_kernel<<<4096, 256, 0, stream>>>(F0, Sc + 7, x, U1, NBSD, Sc + 8);

  ln_kernel<<<Bdim * Sdim, 256, 0, stream>>>(U1, g2, bn2, Sc + 8, U0, Sc + 9);
  quant8_kernel<<<4096, 256, 0, stream>>>(U0, Sc + 9, A8, NBSD / 4);

  dim3 gF1(4 * Ddim / 128, M / 128);             // (32, 64)
  gemm_i8<1><<<gF1, 256, 0, stream>>>(A8, W18, bf1, F, M, 4 * Ddim, Ddim, Sc + 9, Sc + 5, Sc + 10);

  quant8_kernel<<<4096, 256, 0, stream>>>(F, Sc + 10, G8, NBSD);

  // FFN2 with fused residual: u = acc*s + bias + qdq(t) -> d_out, amax Sc11
  gemm_i8<2><<<gP, 256, 0, stream>>>(G8, W28, bf2, out, M, Ddim, 4 * Ddim,
                                     Sc + 10, Sc + 6, Sc + 11, U1, Sc + 8);

  qdq_out_kernel<<<4096, 256, 0, stream>>>(out, Sc + 11, out, NBSD);
}